// Round 6
// baseline (193.739 us; speedup 1.0000x reference)
//
#include <hip/hip_runtime.h>
#include <math.h>

// Problem constants (ShowAttendTellCore)
//   B=1024, D_MODEL=512, N_HEADS=8, D_HEAD=64, N_LEVELS=4, N_POINTS=4
//   T_TOTAL=1920, RNN=512, ENC=512, ATT_HID=512
// Output layout (f32): h2 (524288) | h1 | h2 | c1 | c2   (total 2621440)

typedef __attribute__((ext_vector_type(8))) short          s16x8;
typedef __attribute__((ext_vector_type(8))) unsigned short u16x8;
typedef __attribute__((ext_vector_type(4))) float          f32x4;

#define LOG2E  1.4426950408889634f
#define LOG2E2 2.8853900817779268f

__device__ __forceinline__ float rcpf(float x) { return __builtin_amdgcn_rcpf(x); }
__device__ __forceinline__ float exp2f_fast(float x) { return __builtin_amdgcn_exp2f(x); }
// sigmoid: 1/(1+2^(-x*log2e))   (~1ulp rcp; fine vs 7.4e-2 threshold)
__device__ __forceinline__ float sigf(float x) {
    return rcpf(1.0f + exp2f_fast(-x * LOG2E));
}
// tanh: 1 - 2*rcp(2^(2x*log2e)+1), clamped
__device__ __forceinline__ float tanhf_fast(float x) {
    const float xc = fminf(fmaxf(x, -15.0f), 15.0f);
    const float e2 = exp2f_fast(xc * LOG2E2);
    return 1.0f - 2.0f * rcpf(e2 + 1.0f);
}
__device__ __forceinline__ unsigned short f2bf(float f) {   // RNE f32->bf16
    unsigned u = __float_as_uint(f);
    u += 0x7FFF + ((u >> 16) & 1);
    return (unsigned short)(u >> 16);
}
__device__ __forceinline__ float bf2f(unsigned short h) {
    return __uint_as_float(((unsigned)h) << 16);
}
// async global->LDS, 16B per lane (lane i lands at firstlane_dst + i*16)
__device__ __forceinline__ void gld_lds16(const unsigned short* g, unsigned short* l) {
    __builtin_amdgcn_global_load_lds(
        (const __attribute__((address_space(1))) void*)g,
        (__attribute__((address_space(3))) void*)l, 16, 0, 0);
}

// ---------------- batched f32 -> bf16 strided converts (one launch) --------
struct CvtJob { const float* src; unsigned short* dst; int sld, dld, cols, total; };
struct CvtJobs { CvtJob j[11]; };
__global__ __launch_bounds__(256) void cvt_bf16(CvtJobs cj) {
    const CvtJob jb = cj.j[blockIdx.y];
    const int i = (blockIdx.x * 256 + threadIdx.x) * 4;
    if (i >= jb.total) return;
    const int r = i / jb.cols, c = i - r * jb.cols;
    const float4 v4 = *(const float4*)&jb.src[(size_t)r * jb.sld + c];
    ushort4 o;
    o.x = f2bf(v4.x); o.y = f2bf(v4.y); o.z = f2bf(v4.z); o.w = f2bf(v4.w);
    *(ushort4*)&jb.dst[(size_t)r * jb.dld + c] = o;
}

// transpose-convert: dst[n][k] = bf16(src[k][n]);  src is (K_, N_) row-major
struct TJob { const float* src; unsigned short* dst; int N_, dld, K_, total; };
struct TJobs { TJob j[5]; };
__global__ __launch_bounds__(256) void tcvt_bf16(TJobs tj) {
    const TJob jb = tj.j[blockIdx.y];
    const int i = blockIdx.x * 256 + threadIdx.x;
    if (i >= jb.total) return;
    const int n = i / jb.K_, k = i - n * jb.K_;
    jb.dst[(size_t)n * jb.dld + k] = f2bf(jb.src[(size_t)k * jb.N_ + n]);
}

// bcat = [boff(128) | battw(128) | bh2a(512)]
__global__ __launch_bounds__(768) void bias_cat3(const float* __restrict__ a,
                                                 const float* __restrict__ b,
                                                 const float* __restrict__ c,
                                                 float* __restrict__ dst) {
    const int t = threadIdx.x;
    dst[t] = (t < 128) ? a[t] : (t < 256 ? b[t - 128] : c[t - 256]);
}

// ---------------- LDS-staged bf16 MFMA GEMM (2-phase double-buffer) --------
// C(MxN f32) = A(MxK bf16 rm, lda) @ B^T (B NxK bf16 rm, ldb) + bias
// BM=64 BN=128 BK=32; grid=(N/128, M/64); 256 thr = 4 waves (2x2), wave=32x64.
__global__ __launch_bounds__(256) void sgemm(
    const unsigned short* __restrict__ A, int lda,
    const unsigned short* __restrict__ B, int ldb,
    const float* __restrict__ bias, float* __restrict__ C, int ldc, int K)
{
    __shared__ unsigned short As[2][64 * 32];
    __shared__ unsigned short Bs[2][128 * 32];

    const int tid = threadIdx.x;
    const int w = tid >> 6, lane = tid & 63;
    const int wr = w >> 1, wc = w & 1;
    const int lr = lane & 15, lg = lane >> 4;
    const int bm = blockIdx.y, bn = blockIdx.x;

    const int srow = tid >> 2, sk = (tid & 3) << 3;
    const unsigned short* Ag  = A + (size_t)(bm * 64 + srow) * lda + sk;
    const unsigned short* Bg0 = B + (size_t)(bn * 128 + srow) * ldb + sk;
    const unsigned short* Bg1 = B + (size_t)(bn * 128 + 64 + srow) * ldb + sk;

    f32x4 acc[2][4];
#pragma unroll
    for (int mt = 0; mt < 2; ++mt)
#pragma unroll
        for (int nt = 0; nt < 4; ++nt) acc[mt][nt] = (f32x4){0.f, 0.f, 0.f, 0.f};

    const int nsteps = K >> 5;
    int cur = 0;
    gld_lds16(Ag,  &As[0][tid * 8]);
    gld_lds16(Bg0, &Bs[0][tid * 8]);
    gld_lds16(Bg1, &Bs[0][2048 + tid * 8]);
    asm volatile("s_waitcnt vmcnt(0)" ::: "memory");
    __syncthreads();

    for (int t = 0; t < nsteps; ++t) {
        const int k1 = (t + 1) << 5;
        if (t + 1 < nsteps) {
            gld_lds16(Ag + k1,  &As[cur ^ 1][tid * 8]);
            gld_lds16(Bg0 + k1, &Bs[cur ^ 1][tid * 8]);
            gld_lds16(Bg1 + k1, &Bs[cur ^ 1][2048 + tid * 8]);
        }
        const unsigned short* Ab = &As[cur][0];
        const unsigned short* Bb = &Bs[cur][0];
        s16x8 a[2], bfr[4];
#pragma unroll
        for (int mt = 0; mt < 2; ++mt)
            a[mt] = *(const s16x8*)&Ab[(wr * 32 + mt * 16 + lr) * 32 + lg * 8];
#pragma unroll
        for (int nt = 0; nt < 4; ++nt)
            bfr[nt] = *(const s16x8*)&Bb[(wc * 64 + nt * 16 + lr) * 32 + lg * 8];
#pragma unroll
        for (int mt = 0; mt < 2; ++mt)
#pragma unroll
            for (int nt = 0; nt < 4; ++nt)
                acc[mt][nt] = __builtin_amdgcn_mfma_f32_16x16x32_bf16(
                    a[mt], bfr[nt], acc[mt][nt], 0, 0, 0);
        asm volatile("s_waitcnt vmcnt(0)" ::: "memory");
        __syncthreads();
        cur ^= 1;
    }
#pragma unroll
    for (int nt = 0; nt < 4; ++nt) {
        const int col = bn * 128 + wc * 64 + nt * 16 + lr;
        const float bb = bias ? bias[col] : 0.0f;
#pragma unroll
        for (int mt = 0; mt < 2; ++mt) {
            const int rbase = bm * 64 + wr * 32 + mt * 16 + lg * 4;
#pragma unroll
            for (int r = 0; r < 4; ++r)
                C[(size_t)(rbase + r) * ldc + col] = acc[mt][nt][r] + bb;
        }
    }
}

// ---------------- direct-global bf16 MFMA GEMM (small GEMMs only) ----------
__global__ __launch_bounds__(256) void mgemm(
    const unsigned short* __restrict__ A, int lda,
    const unsigned short* __restrict__ B, int ldb,
    const float* __restrict__ bias, float* __restrict__ C, int ldc, int K)
{
    const int tid = threadIdx.x;
    const int w = tid >> 6, lane = tid & 63;
    const int wm = w >> 1, wn = w & 1;
    const int lr = lane & 15, lg = lane >> 4;
    const int row0 = blockIdx.y * 64 + wm * 32;
    const int col0 = blockIdx.x * 64 + wn * 32;

    const unsigned short* Ap = A + (size_t)(row0 + lr) * lda + lg * 8;
    const unsigned short* Bp = B + (size_t)(col0 + lr) * ldb + lg * 8;

    f32x4 acc[2][2];
#pragma unroll
    for (int mt = 0; mt < 2; ++mt)
#pragma unroll
        for (int nt = 0; nt < 2; ++nt) acc[mt][nt] = (f32x4){0.f, 0.f, 0.f, 0.f};

    for (int k0 = 0; k0 < K; k0 += 64) {
        s16x8 a[2][2], bf[2][2];
#pragma unroll
        for (int mt = 0; mt < 2; ++mt)
#pragma unroll
            for (int u = 0; u < 2; ++u)
                a[mt][u] = *(const s16x8*)&Ap[(size_t)mt * 16 * lda + k0 + u * 32];
#pragma unroll
        for (int nt = 0; nt < 2; ++nt)
#pragma unroll
            for (int u = 0; u < 2; ++u)
                bf[nt][u] = *(const s16x8*)&Bp[(size_t)nt * 16 * ldb + k0 + u * 32];
#pragma unroll
        for (int u = 0; u < 2; ++u)
#pragma unroll
            for (int mt = 0; mt < 2; ++mt)
#pragma unroll
                for (int nt = 0; nt < 2; ++nt)
                    acc[mt][nt] = __builtin_amdgcn_mfma_f32_16x16x32_bf16(
                        a[mt][u], bf[nt][u], acc[mt][nt], 0, 0, 0);
    }
#pragma unroll
    for (int nt = 0; nt < 2; ++nt) {
        const int col = col0 + nt * 16 + lr;
        const float bb = bias ? bias[col] : 0.0f;
#pragma unroll
        for (int mt = 0; mt < 2; ++mt) {
            const int rbase = row0 + mt * 16 + lg * 4;
#pragma unroll
            for (int r = 0; r < 4; ++r)
                C[(size_t)(rbase + r) * ldc + col] = acc[mt][nt][r] + bb;
        }
    }
}

// ---------------- fused deformable sampling + context attention ------------
// obat (B,768) = [off(128) | aw_raw(128) | atth(512)]  (biases included)
__global__ __launch_bounds__(512, 4) void fused_att(
    const float* __restrict__ v,       // (1920, 512)
    const float* __restrict__ obat,    // (B, 768)
    const float* __restrict__ refp,    // (B, 4)
    const int*   __restrict__ shapes,  // (4,)
    const int*   __restrict__ starts,  // (4,)
    const unsigned short* __restrict__ Wb,  // (512, 64) bf16, = Wctx^T
    const float* __restrict__ bctx,    // (512,)
    const float* __restrict__ walpha,  // (512,)
    unsigned short* __restrict__ attdst)    // bf16, row stride 2048
{
    __shared__ unsigned short cf[128 * 64];   // 16 KB, XOR chunk-swizzled
    __shared__ float awb[128];
    __shared__ float dsum[128];
    __shared__ float dots4[4][128];

    const int b    = blockIdx.x;
    const int tid  = threadIdx.x;
    const int w    = tid >> 6, lane = tid & 63;
    const int wm   = w >> 2,   wn   = w & 3;
    const int lr   = lane & 15, lg  = lane >> 4;

    // early-issue first B-fragment + per-col scalars (covers phases 0-1 latency)
    s16x8 nb0, nb1; float nbc, nat, nwa;
    {
        const int col = (wn * 8) * 16 + lr;
        nb0 = *(const s16x8*)&Wb[col * 64 + lg * 8];
        nb1 = *(const s16x8*)&Wb[col * 64 + 32 + lg * 8];
        nbc = bctx[col]; nat = obat[b * 768 + 256 + col]; nwa = walpha[col];
    }

    // phase 0: attention-weight softmax (16 per head)
    if (tid < 128) awb[tid] = obat[b * 768 + 128 + tid];
    __syncthreads();
    if (tid < 8) {
        float mx = -1e30f;
        for (int i = 0; i < 16; ++i) mx = fmaxf(mx, awb[tid * 16 + i]);
        float sum = 0.f;
        for (int i = 0; i < 16; ++i) { float e = exp2f_fast((awb[tid * 16 + i] - mx) * LOG2E); awb[tid * 16 + i] = e; sum += e; }
        float inv = rcpf(sum);
        for (int i = 0; i < 16; ++i) awb[tid * 16 + i] *= inv;
    }
    __syncthreads();

    // phase 1: bilinear sampling -> cf[p][d] = bf16(samp[d] * aw[p])
    {
        const int pg  = tid >> 2;
        const int sub = tid & 3;
        const int d0  = sub * 16;
        const int h   = pg >> 4;
        const int l   = (pg & 15) >> 2;
        const int Tlen = shapes[l];
        const int st   = starts[l];
        const float T  = (float)Tlen;
        const float refv = refp[b * 4 + l];
        const float offv = obat[b * 768 + pg];
        const float awv  = awb[pg];
        const float x   = (refv + offv * rcpf(T)) * T - 0.5f;  // exact: T is 2^k
        const float x0f = floorf(x);
        const float w1  = x - x0f;
        const int   x0  = (int)x0f;
        const float w0s = (x0 >= 0 && x0 < Tlen) ? (1.0f - w1) : 0.0f;
        const float w1s = (x0 + 1 >= 0 && x0 + 1 < Tlen) ? w1 : 0.0f;
        const int i0 = (min(max(x0, 0), Tlen - 1) + st) * 512 + h * 64;
        const int i1 = (min(max(x0 + 1, 0), Tlen - 1) + st) * 512 + h * 64;
        u16x8 o0, o1;
#pragma unroll
        for (int q = 0; q < 4; ++q) {
            const float4 a  = *(const float4*)&v[i0 + d0 + q * 4];
            const float4 bq = *(const float4*)&v[i1 + d0 + q * 4];
            unsigned short e0 = f2bf((a.x * w0s + bq.x * w1s) * awv);
            unsigned short e1 = f2bf((a.y * w0s + bq.y * w1s) * awv);
            unsigned short e2 = f2bf((a.z * w0s + bq.z * w1s) * awv);
            unsigned short e3 = f2bf((a.w * w0s + bq.w * w1s) * awv);
            if (q == 0) { o0[0] = e0; o0[1] = e1; o0[2] = e2; o0[3] = e3; }
            if (q == 1) { o0[4] = e0; o0[5] = e1; o0[6] = e2; o0[7] = e3; }
            if (q == 2) { o1[0] = e0; o1[1] = e1; o1[2] = e2; o1[3] = e3; }
            if (q == 3) { o1[4] = e0; o1[5] = e1; o1[6] = e2; o1[7] = e3; }
        }
        const int c0 = (sub * 2)     ^ (pg & 7);
        const int c1 = (sub * 2 + 1) ^ (pg & 7);
        *(u16x8*)&cf[pg * 64 + c0 * 8] = o0;
        *(u16x8*)&cf[pg * 64 + c1 * 8] = o1;
    }
    __syncthreads();

    // phase 2: dots[p] = sum_j tanh((cf@Wctx)[p][j] + bctx[j]+atth[j]) * walpha[j]
    {
        s16x8 afrag[4][2];
#pragma unroll
        for (int mt = 0; mt < 4; ++mt) {
            const int row = wm * 64 + mt * 16 + lr;
#pragma unroll
            for (int ks = 0; ks < 2; ++ks) {
                const int ch = (ks * 4 + lg) ^ (row & 7);
                afrag[mt][ks] = *(const s16x8*)&cf[row * 64 + ch * 8];
            }
        }
        f32x4 part[4];
#pragma unroll
        for (int mt = 0; mt < 4; ++mt) part[mt] = (f32x4){0.f, 0.f, 0.f, 0.f};

#pragma unroll
        for (int nt = 0; nt < 8; ++nt) {
            const s16x8 b0 = nb0, b1 = nb1;
            const float bav = nbc + nat, wav = nwa;
            if (nt < 7) {   // depth-1 prefetch: next iter's operands
                const int ncol = (wn * 8 + nt + 1) * 16 + lr;
                nb0 = *(const s16x8*)&Wb[ncol * 64 + lg * 8];
                nb1 = *(const s16x8*)&Wb[ncol * 64 + 32 + lg * 8];
                nbc = bctx[ncol]; nat = obat[b * 768 + 256 + ncol]; nwa = walpha[ncol];
            }
#pragma unroll
            for (int mt = 0; mt < 4; ++mt) {
                f32x4 acc = {0.f, 0.f, 0.f, 0.f};
                acc = __builtin_amdgcn_mfma_f32_16x16x32_bf16(afrag[mt][0], b0, acc, 0, 0, 0);
                acc = __builtin_amdgcn_mfma_f32_16x16x32_bf16(afrag[mt][1], b1, acc, 0, 0, 0);
#pragma unroll
                for (int r = 0; r < 4; ++r)
                    part[mt][r] += tanhf_fast(acc[r] + bav) * wav;
            }
        }
#pragma unroll
        for (int mt = 0; mt < 4; ++mt) {
#pragma unroll
            for (int r = 0; r < 4; ++r) {
                float s = part[mt][r];
                s += __shfl_xor(s, 1); s += __shfl_xor(s, 2);
                s += __shfl_xor(s, 4); s += __shfl_xor(s, 8);
                if (lr == 0) dots4[wn][wm * 64 + mt * 16 + lg * 4 + r] = s;
            }
        }
    }
    __syncthreads();
    if (tid < 128)
        dsum[tid] = dots4[0][tid] + dots4[1][tid] + dots4[2][tid] + dots4[3][tid];
    __syncthreads();

    // phase 3: softmax over the 16 points of each head
    if (tid < 8) {
        float mx = -1e30f;
        for (int i = 0; i < 16; ++i) mx = fmaxf(mx, dsum[tid * 16 + i]);
        float sum = 0.f;
        for (int i = 0; i < 16; ++i) { float e = exp2f_fast((dsum[tid * 16 + i] - mx) * LOG2E); dsum[tid * 16 + i] = e; sum += e; }
        float inv = rcpf(sum);
        for (int i = 0; i < 16; ++i) dsum[tid * 16 + i] *= inv;
    }
    __syncthreads();

    // phase 4: att_res (bf16 into Acat)
    {
        const int h = tid >> 6, d = tid & 63;
        const int ch = d >> 3, e = d & 7;
        float s = 0.f;
#pragma unroll
        for (int p = 0; p < 16; ++p) {
            const int row = h * 16 + p;
            s += dsum[h * 16 + p] * bf2f(cf[row * 64 + ((ch ^ (row & 7)) * 8) + e]);
        }
        attdst[(size_t)b * 2048 + tid] = f2bf(s);
    }
}

// LSTM elementwise; optionally emits bf16 h into hbf (row stride 1024)
__global__ __launch_bounds__(256) void lstm_act(
    const float* __restrict__ g, const float* __restrict__ c_in,
    float* __restrict__ h_out, float* __restrict__ h_out2,
    unsigned short* __restrict__ hbf, float* __restrict__ c_out)
{
    const int idx = blockIdx.x * 256 + threadIdx.x;  // 0..524287
    const int m = idx >> 9, j = idx & 511;
    const float* gr = g + (size_t)m * 2048;
    const float gi = gr[j], gf = gr[512 + j], gg = gr[1024 + j], go = gr[1536 + j];
    const float c  = c_in[idx];
    const float c2 = sigf(gf) * c + sigf(gi) * tanhf_fast(gg);
    const float h2 = sigf(go) * tanhf_fast(c2);
    h_out[idx] = h2;
    if (h_out2) h_out2[idx] = h2;
    if (hbf) hbf[(size_t)m * 1024 + j] = f2bf(h2);
    c_out[idx] = c2;
}

extern "C" void kernel_launch(void* const* d_in, const int* in_sizes, int n_in,
                              void* d_out, int out_size, void* d_ws, size_t ws_size,
                              hipStream_t stream) {
    const float* xt     = (const float*)d_in[0];
    const float* h0     = (const float*)d_in[1];   // (2,1024,512)
    const float* c0     = (const float*)d_in[2];
    const float* query  = (const float*)d_in[3];   // (1,1024,512)
    const float* refp   = (const float*)d_in[4];   // (1,1024,4,1)
    const float* inflat = (const float*)d_in[5];   // (1,1920,512)
    const int*   shapes = (const int*)d_in[6];
    const int*   starts = (const int*)d_in[7];
    const float* Wv     = (const float*)d_in[9];   // (512,512) (K,N)
    const float* bv     = (const float*)d_in[10];
    const float* Woff   = (const float*)d_in[11];  // (1024,128) (K,N)
    const float* boff   = (const float*)d_in[12];
    const float* Wattw  = (const float*)d_in[13];  // (1024,128)
    const float* battw  = (const float*)d_in[14];
    const float* Wctx   = (const float*)d_in[15];  // (64,512)
    const float* bctx   = (const float*)d_in[16];
    const float* Wh2a   = (const float*)d_in[17];  // (512,512) (K,N)
    const float* bh2a   = (const float*)d_in[18];
    const float* walpha = (const float*)d_in[19];
    const float* Wih0   = (const float*)d_in[21];  // (2048,1536) (N,K)
    const float* Whh0   = (const float*)d_in[22];  // (2048,512)
    const float* Wih1   = (const float*)d_in[23];  // (2048,512)
    const float* Whh1   = (const float*)d_in[24];  // (2048,512)

    float* out = (float*)d_out;
    float* ws  = (float*)d_ws;

    // ws layout (f32 units), lifetime-overlapped; total 8585216 f32 = 34.4 MB
    float*          v     = ws;                                   // 983040
    float*          obat  = ws + 983040;                          // 1024x768 [off|aw|atth]
    unsigned short* Acat  = (unsigned short*)(ws + 1769472);      // 1024x2048 bf16
    unsigned short* Bcat0 = (unsigned short*)(ws + 2818048);      // 2048x2048 bf16
    float*          g     = ws + 4915200;                         // 2097152
    //   early-phase tenants of the g region (dead before gemm0 writes g):
    unsigned short* Ainf  = (unsigned short*)(ws + 4915200);      // 1920x512 bf16
    unsigned short* Wvt   = (unsigned short*)(ws + 5406720);      // 512x512 bf16
    unsigned short* Wcat  = (unsigned short*)(ws + 5537792);      // 768x1024 bf16 [Woff^T|Wattw^T|Wh2a^T pad0]
    unsigned short* Ahq   = (unsigned short*)(ws + 5931008);      // 1024x1024 bf16
    unsigned short* Wb    = (unsigned short*)(ws + 6455296);      // 512x64 bf16 (Wctx^T)
    float*          bcat  = ws + 6471680;                         // 768
    unsigned short* Ag1   = (unsigned short*)(ws + 7012352);      // 1024x1024 bf16
    unsigned short* Bcat1 = (unsigned short*)(ws + 7536640);      // 2048x1024 bf16

    const float* h00    = h0;
    const float* h_last = h0 + 524288;     // h0[1]
    float* h1  = out + 524288;             // h_new[0]
    float* c1  = out + 1572864;            // c_new[0]
    float* h2a = out;                      // first output
    float* h2b = out + 1048576;            // h_new[1]
    float* c2  = out + 2097152;            // c_new[1]

    // --- prep: converts (1 launch), memset pad, transposes (1 launch), biases ---
    { CvtJobs cj;
      cj.j[0]  = { xt,     Acat,          512,  2048, 512,  524288 };
      cj.j[1]  = { query,  Acat + 1024,   512,  2048, 512,  524288 };
      cj.j[2]  = { h00,    Acat + 1536,   512,  2048, 512,  524288 };
      cj.j[3]  = { h_last, Ahq,           512,  1024, 512,  524288 };
      cj.j[4]  = { query,  Ahq + 512,     512,  1024, 512,  524288 };
      cj.j[5]  = { h_last, Ag1 + 512,     512,  1024, 512,  524288 };
      cj.j[6]  = { Wih0,   Bcat0,         1536, 2048, 1536, 3145728 };
      cj.j[7]  = { Whh0,   Bcat0 + 1536,  512,  2048, 512,  1048576 };
      cj.j[8]  = { Wih1,   Bcat1,         512,  1024, 512,  1048576 };
      cj.j[9]  = { Whh1,   Bcat1 + 512,   512,  1024, 512,  1048576 };
      cj.j[10] = { inflat, Ainf,          512,  512,  512,  983040 };
      cvt_bf16<<<dim3(3072, 11), 256, 0, stream>>>(cj); }
    hipMemsetAsync(Wcat, 0, (size_t)768 * 1024 * 2, stream);   // zero K-pad for Wh2a rows
    { TJobs tj;
      tj.j[0] = { Wv,    Wvt,               512, 512,  512,  262144 };
      tj.j[1] = { Woff,  Wcat,              128, 1024, 1024, 131072 };
      tj.j[2] = { Wattw, Wcat + 128 * 1024, 128, 1024, 1024, 131072 };
      tj.j[3] = { Wh2a,  Wcat + 256 * 1024, 512, 1024, 512,  262144 };
      tj.j[4] = { Wctx,  Wb,                512, 64,   64,   32768 };
      tcvt_bf16<<<dim3(1024, 5), 256, 0, stream>>>(tj); }
    bias_cat3<<<1, 768, 0, stream>>>(boff, battw, bh2a, bcat);

    // --- GEMMs (bf16 MFMA) ---
    // value: v = inflat @ Wv + bv          (1920x512, K=512)  [LDS-staged]
    sgemm<<<dim3(4, 30), 256, 0, stream>>>(Ainf, 512, Wvt, 512, bv, v, 512, 512);
    // obat = [h_last|query] @ [Woff|Wattw|Wh2a pad] + [boff|battw|bh2a]  (1024x768, K=1024)
    mgemm<<<dim3(12, 16), 256, 0, stream>>>(Ahq, 1024, Wcat, 1024, bcat, obat, 768, 1024);

    // --- fused deformable sampling + context attention (writes Acat[:,512:1024]) ---
    fused_att<<<1024, 512, 0, stream>>>(v, obat, refp, shapes, starts,
                                        Wb, bctx, walpha, Acat + 512);

    // g0 = [xt|att_res|query|h0[0]] @ [Wih0|Whh0]^T    (1024x2048, K=2048)  [LDS-staged]
    sgemm<<<dim3(16, 16), 256, 0, stream>>>(Acat, 2048, Bcat0, 2048, nullptr, g, 2048, 2048);
    lstm_act<<<2048, 256, 0, stream>>>(g, c0, h1, nullptr, Ag1, c1);
    // g1 = [h1|h0[1]] @ [Wih1|Whh1]^T                  (1024x2048, K=1024)  [LDS-staged]
    sgemm<<<dim3(16, 16), 256, 0, stream>>>(Ag1, 1024, Bcat1, 1024, nullptr, g, 2048, 1024);
    lstm_act<<<2048, 256, 0, stream>>>(g, c0 + 524288, h2a, h2b, nullptr, c2);
}

// Round 7
// 186.706 us; speedup vs baseline: 1.0377x; 1.0377x over previous
//
#include <hip/hip_runtime.h>
#include <math.h>

// Problem constants (ShowAttendTellCore)
//   B=1024, D_MODEL=512, N_HEADS=8, D_HEAD=64, N_LEVELS=4, N_POINTS=4
//   T_TOTAL=1920, RNN=512, ENC=512, ATT_HID=512
// Output layout (f32): h2 (524288) | h1 | h2 | c1 | c2   (total 2621440)

typedef __attribute__((ext_vector_type(8))) short          s16x8;
typedef __attribute__((ext_vector_type(8))) unsigned short u16x8;
typedef __attribute__((ext_vector_type(4))) float          f32x4;

#define LOG2E  1.4426950408889634f
#define LOG2E2 2.8853900817779268f

__device__ __forceinline__ float rcpf(float x) { return __builtin_amdgcn_rcpf(x); }
__device__ __forceinline__ float exp2f_fast(float x) { return __builtin_amdgcn_exp2f(x); }
// sigmoid: 1/(1+2^(-x*log2e))   (~1ulp rcp; fine vs 7.4e-2 threshold)
__device__ __forceinline__ float sigf(float x) {
    return rcpf(1.0f + exp2f_fast(-x * LOG2E));
}
// tanh: 1 - 2*rcp(2^(2x*log2e)+1), clamped
__device__ __forceinline__ float tanhf_fast(float x) {
    const float xc = fminf(fmaxf(x, -15.0f), 15.0f);
    const float e2 = exp2f_fast(xc * LOG2E2);
    return 1.0f - 2.0f * rcpf(e2 + 1.0f);
}
__device__ __forceinline__ unsigned short f2bf(float f) {   // RNE f32->bf16
    unsigned u = __float_as_uint(f);
    u += 0x7FFF + ((u >> 16) & 1);
    return (unsigned short)(u >> 16);
}
__device__ __forceinline__ float bf2f(unsigned short h) {
    return __uint_as_float(((unsigned)h) << 16);
}
// async global->LDS, 16B per lane (lane i lands at firstlane_dst + i*16)
__device__ __forceinline__ void gld_lds16(const unsigned short* g, unsigned short* l) {
    __builtin_amdgcn_global_load_lds(
        (const __attribute__((address_space(1))) void*)g,
        (__attribute__((address_space(3))) void*)l, 16, 0, 0);
}

// ---------------- batched f32 -> bf16 strided converts (one launch) --------
struct CvtJob { const float* src; unsigned short* dst; int sld, dld, cols, total; };
struct CvtJobs { CvtJob j[11]; };
__global__ __launch_bounds__(256) void cvt_bf16(CvtJobs cj) {
    const CvtJob jb = cj.j[blockIdx.y];
    const int i = (blockIdx.x * 256 + threadIdx.x) * 4;
    if (i >= jb.total) return;
    const int r = i / jb.cols, c = i - r * jb.cols;
    const float4 v4 = *(const float4*)&jb.src[(size_t)r * jb.sld + c];
    ushort4 o;
    o.x = f2bf(v4.x); o.y = f2bf(v4.y); o.z = f2bf(v4.z); o.w = f2bf(v4.w);
    *(ushort4*)&jb.dst[(size_t)r * jb.dld + c] = o;
}

// transpose-convert: dst[n][k] = bf16(src[k][n]);  src is (K_, N_) row-major
struct TJob { const float* src; unsigned short* dst; int N_, dld, K_, total; };
struct TJobs { TJob j[5]; };
__global__ __launch_bounds__(256) void tcvt_bf16(TJobs tj) {
    const TJob jb = tj.j[blockIdx.y];
    const int i = blockIdx.x * 256 + threadIdx.x;
    if (i >= jb.total) return;
    const int n = i / jb.K_, k = i - n * jb.K_;
    jb.dst[(size_t)n * jb.dld + k] = f2bf(jb.src[(size_t)k * jb.N_ + n]);
}

// bcat = [boff(128) | battw(128) | bh2a(512)]
__global__ __launch_bounds__(768) void bias_cat3(const float* __restrict__ a,
                                                 const float* __restrict__ b,
                                                 const float* __restrict__ c,
                                                 float* __restrict__ dst) {
    const int t = threadIdx.x;
    dst[t] = (t < 128) ? a[t] : (t < 256 ? b[t - 128] : c[t - 256]);
}

// ---------------- LDS-staged bf16 MFMA GEMM (2-phase double-buffer) --------
// C(MxN f32) = A(MxK bf16 rm, lda) @ B^T (B NxK bf16 rm, ldb) + bias
// BM=64 BN=128 BK=32; grid=(N/128, M/64); 256 thr = 4 waves (2x2), wave=32x64.
__global__ __launch_bounds__(256) void sgemm(
    const unsigned short* __restrict__ A, int lda,
    const unsigned short* __restrict__ B, int ldb,
    const float* __restrict__ bias, float* __restrict__ C, int ldc, int K)
{
    __shared__ unsigned short As[2][64 * 32];
    __shared__ unsigned short Bs[2][128 * 32];

    const int tid = threadIdx.x;
    const int w = tid >> 6, lane = tid & 63;
    const int wr = w >> 1, wc = w & 1;
    const int lr = lane & 15, lg = lane >> 4;
    const int bm = blockIdx.y, bn = blockIdx.x;

    const int srow = tid >> 2, sk = (tid & 3) << 3;
    const unsigned short* Ag  = A + (size_t)(bm * 64 + srow) * lda + sk;
    const unsigned short* Bg0 = B + (size_t)(bn * 128 + srow) * ldb + sk;
    const unsigned short* Bg1 = B + (size_t)(bn * 128 + 64 + srow) * ldb + sk;

    f32x4 acc[2][4];
#pragma unroll
    for (int mt = 0; mt < 2; ++mt)
#pragma unroll
        for (int nt = 0; nt < 4; ++nt) acc[mt][nt] = (f32x4){0.f, 0.f, 0.f, 0.f};

    const int nsteps = K >> 5;
    int cur = 0;
    gld_lds16(Ag,  &As[0][tid * 8]);
    gld_lds16(Bg0, &Bs[0][tid * 8]);
    gld_lds16(Bg1, &Bs[0][2048 + tid * 8]);
    asm volatile("s_waitcnt vmcnt(0)" ::: "memory");
    __syncthreads();

    for (int t = 0; t < nsteps; ++t) {
        const int k1 = (t + 1) << 5;
        if (t + 1 < nsteps) {
            gld_lds16(Ag + k1,  &As[cur ^ 1][tid * 8]);
            gld_lds16(Bg0 + k1, &Bs[cur ^ 1][tid * 8]);
            gld_lds16(Bg1 + k1, &Bs[cur ^ 1][2048 + tid * 8]);
        }
        const unsigned short* Ab = &As[cur][0];
        const unsigned short* Bb = &Bs[cur][0];
        s16x8 a[2], bfr[4];
#pragma unroll
        for (int mt = 0; mt < 2; ++mt)
            a[mt] = *(const s16x8*)&Ab[(wr * 32 + mt * 16 + lr) * 32 + lg * 8];
#pragma unroll
        for (int nt = 0; nt < 4; ++nt)
            bfr[nt] = *(const s16x8*)&Bb[(wc * 64 + nt * 16 + lr) * 32 + lg * 8];
#pragma unroll
        for (int mt = 0; mt < 2; ++mt)
#pragma unroll
            for (int nt = 0; nt < 4; ++nt)
                acc[mt][nt] = __builtin_amdgcn_mfma_f32_16x16x32_bf16(
                    a[mt], bfr[nt], acc[mt][nt], 0, 0, 0);
        asm volatile("s_waitcnt vmcnt(0)" ::: "memory");
        __syncthreads();
        cur ^= 1;
    }
#pragma unroll
    for (int nt = 0; nt < 4; ++nt) {
        const int col = bn * 128 + wc * 64 + nt * 16 + lr;
        const float bb = bias ? bias[col] : 0.0f;
#pragma unroll
        for (int mt = 0; mt < 2; ++mt) {
            const int rbase = bm * 64 + wr * 32 + mt * 16 + lg * 4;
#pragma unroll
            for (int r = 0; r < 4; ++r)
                C[(size_t)(rbase + r) * ldc + col] = acc[mt][nt][r] + bb;
        }
    }
}

// ---------------- direct-global bf16 MFMA GEMM (small GEMMs only) ----------
__global__ __launch_bounds__(256) void mgemm(
    const unsigned short* __restrict__ A, int lda,
    const unsigned short* __restrict__ B, int ldb,
    const float* __restrict__ bias, float* __restrict__ C, int ldc, int K)
{
    const int tid = threadIdx.x;
    const int w = tid >> 6, lane = tid & 63;
    const int wm = w >> 1, wn = w & 1;
    const int lr = lane & 15, lg = lane >> 4;
    const int row0 = blockIdx.y * 64 + wm * 32;
    const int col0 = blockIdx.x * 64 + wn * 32;

    const unsigned short* Ap = A + (size_t)(row0 + lr) * lda + lg * 8;
    const unsigned short* Bp = B + (size_t)(col0 + lr) * ldb + lg * 8;

    f32x4 acc[2][2];
#pragma unroll
    for (int mt = 0; mt < 2; ++mt)
#pragma unroll
        for (int nt = 0; nt < 2; ++nt) acc[mt][nt] = (f32x4){0.f, 0.f, 0.f, 0.f};

    for (int k0 = 0; k0 < K; k0 += 64) {
        s16x8 a[2][2], bf[2][2];
#pragma unroll
        for (int mt = 0; mt < 2; ++mt)
#pragma unroll
            for (int u = 0; u < 2; ++u)
                a[mt][u] = *(const s16x8*)&Ap[(size_t)mt * 16 * lda + k0 + u * 32];
#pragma unroll
        for (int nt = 0; nt < 2; ++nt)
#pragma unroll
            for (int u = 0; u < 2; ++u)
                bf[nt][u] = *(const s16x8*)&Bp[(size_t)nt * 16 * ldb + k0 + u * 32];
#pragma unroll
        for (int u = 0; u < 2; ++u)
#pragma unroll
            for (int mt = 0; mt < 2; ++mt)
#pragma unroll
                for (int nt = 0; nt < 2; ++nt)
                    acc[mt][nt] = __builtin_amdgcn_mfma_f32_16x16x32_bf16(
                        a[mt][u], bf[nt][u], acc[mt][nt], 0, 0, 0);
    }
#pragma unroll
    for (int nt = 0; nt < 2; ++nt) {
        const int col = col0 + nt * 16 + lr;
        const float bb = bias ? bias[col] : 0.0f;
#pragma unroll
        for (int mt = 0; mt < 2; ++mt) {
            const int rbase = row0 + mt * 16 + lg * 4;
#pragma unroll
            for (int r = 0; r < 4; ++r)
                C[(size_t)(rbase + r) * ldc + col] = acc[mt][nt][r] + bb;
        }
    }
}

// ---------------- fused deformable sampling + context attention ------------
// obat (B,768) = [off(128) | aw_raw(128) | atth(512)]  (biases included)
// R5-proven structure: ba/wal staged in LDS, in-loop global B-fragment loads.
__global__ __launch_bounds__(512, 4) void fused_att(
    const float* __restrict__ v,       // (1920, 512)
    const float* __restrict__ obat,    // (B, 768)
    const float* __restrict__ refp,    // (B, 4)
    const int*   __restrict__ shapes,  // (4,)
    const int*   __restrict__ starts,  // (4,)
    const unsigned short* __restrict__ Wb,  // (512, 64) bf16, = Wctx^T
    const float* __restrict__ bctx,    // (512,)
    const float* __restrict__ walpha,  // (512,)
    unsigned short* __restrict__ attdst)    // bf16, row stride 2048
{
    __shared__ unsigned short cf[128 * 64];   // 16 KB, XOR chunk-swizzled
    __shared__ float ba[512];                 // bctx + atth[b]
    __shared__ float wal[512];
    __shared__ float awb[128];
    __shared__ float dsum[128];
    __shared__ float dots4[4][128];

    const int b   = blockIdx.x;
    const int tid = threadIdx.x;

    // phase 0: attention-weight softmax (16 per head)
    if (tid < 128) awb[tid] = obat[b * 768 + 128 + tid];
    __syncthreads();
    if (tid < 8) {
        float mx = -1e30f;
        for (int i = 0; i < 16; ++i) mx = fmaxf(mx, awb[tid * 16 + i]);
        float sum = 0.f;
        for (int i = 0; i < 16; ++i) { float e = exp2f_fast((awb[tid * 16 + i] - mx) * LOG2E); awb[tid * 16 + i] = e; sum += e; }
        float inv = rcpf(sum);
        for (int i = 0; i < 16; ++i) awb[tid * 16 + i] *= inv;
    }
    __syncthreads();

    // phase 1: bilinear sampling -> cf[p][d] = bf16(samp[d] * aw[p]); stage ba/wal
    ba[tid]  = bctx[tid] + obat[b * 768 + 256 + tid];
    wal[tid] = walpha[tid];
    {
        const int pg  = tid >> 2;
        const int sub = tid & 3;
        const int d0  = sub * 16;
        const int h   = pg >> 4;
        const int l   = (pg & 15) >> 2;
        const int Tlen = shapes[l];
        const int st   = starts[l];
        const float T  = (float)Tlen;
        const float refv = refp[b * 4 + l];
        const float offv = obat[b * 768 + pg];
        const float awv  = awb[pg];
        const float x   = (refv + offv * rcpf(T)) * T - 0.5f;  // exact: T is 2^k
        const float x0f = floorf(x);
        const float w1  = x - x0f;
        const int   x0  = (int)x0f;
        const float w0s = (x0 >= 0 && x0 < Tlen) ? (1.0f - w1) : 0.0f;
        const float w1s = (x0 + 1 >= 0 && x0 + 1 < Tlen) ? w1 : 0.0f;
        const int i0 = (min(max(x0, 0), Tlen - 1) + st) * 512 + h * 64;
        const int i1 = (min(max(x0 + 1, 0), Tlen - 1) + st) * 512 + h * 64;
        u16x8 o0, o1;
#pragma unroll
        for (int q = 0; q < 4; ++q) {
            const float4 a  = *(const float4*)&v[i0 + d0 + q * 4];
            const float4 bq = *(const float4*)&v[i1 + d0 + q * 4];
            unsigned short e0 = f2bf((a.x * w0s + bq.x * w1s) * awv);
            unsigned short e1 = f2bf((a.y * w0s + bq.y * w1s) * awv);
            unsigned short e2 = f2bf((a.z * w0s + bq.z * w1s) * awv);
            unsigned short e3 = f2bf((a.w * w0s + bq.w * w1s) * awv);
            if (q == 0) { o0[0] = e0; o0[1] = e1; o0[2] = e2; o0[3] = e3; }
            if (q == 1) { o0[4] = e0; o0[5] = e1; o0[6] = e2; o0[7] = e3; }
            if (q == 2) { o1[0] = e0; o1[1] = e1; o1[2] = e2; o1[3] = e3; }
            if (q == 3) { o1[4] = e0; o1[5] = e1; o1[6] = e2; o1[7] = e3; }
        }
        const int c0 = (sub * 2)     ^ (pg & 7);
        const int c1 = (sub * 2 + 1) ^ (pg & 7);
        *(u16x8*)&cf[pg * 64 + c0 * 8] = o0;
        *(u16x8*)&cf[pg * 64 + c1 * 8] = o1;
    }
    __syncthreads();

    // phase 2: dots[p] = sum_j tanh((cf@Wctx)[p][j] + ba[j]) * wal[j]  via MFMA
    {
        const int w    = tid >> 6, lane = tid & 63;
        const int wm   = w >> 2, wn = w & 3;
        const int lr   = lane & 15, lg = lane >> 4;

        s16x8 afrag[4][2];
#pragma unroll
        for (int mt = 0; mt < 4; ++mt) {
            const int row = wm * 64 + mt * 16 + lr;
#pragma unroll
            for (int ks = 0; ks < 2; ++ks) {
                const int ch = (ks * 4 + lg) ^ (row & 7);
                afrag[mt][ks] = *(const s16x8*)&cf[row * 64 + ch * 8];
            }
        }
        f32x4 part[4];
#pragma unroll
        for (int mt = 0; mt < 4; ++mt) part[mt] = (f32x4){0.f, 0.f, 0.f, 0.f};

        for (int nt = 0; nt < 8; ++nt) {
            const int ct  = wn * 8 + nt;
            const int col = ct * 16 + lr;
            const s16x8 b0 = *(const s16x8*)&Wb[col * 64 + lg * 8];
            const s16x8 b1 = *(const s16x8*)&Wb[col * 64 + 32 + lg * 8];
            const float bav = ba[col], wav = wal[col];
#pragma unroll
            for (int mt = 0; mt < 4; ++mt) {
                f32x4 acc = {0.f, 0.f, 0.f, 0.f};
                acc = __builtin_amdgcn_mfma_f32_16x16x32_bf16(afrag[mt][0], b0, acc, 0, 0, 0);
                acc = __builtin_amdgcn_mfma_f32_16x16x32_bf16(afrag[mt][1], b1, acc, 0, 0, 0);
#pragma unroll
                for (int r = 0; r < 4; ++r)
                    part[mt][r] += tanhf_fast(acc[r] + bav) * wav;
            }
        }
#pragma unroll
        for (int mt = 0; mt < 4; ++mt) {
#pragma unroll
            for (int r = 0; r < 4; ++r) {
                float s = part[mt][r];
                s += __shfl_xor(s, 1); s += __shfl_xor(s, 2);
                s += __shfl_xor(s, 4); s += __shfl_xor(s, 8);
                if (lr == 0) dots4[wn][wm * 64 + mt * 16 + lg * 4 + r] = s;
            }
        }
    }
    __syncthreads();
    if (tid < 128)
        dsum[tid] = dots4[0][tid] + dots4[1][tid] + dots4[2][tid] + dots4[3][tid];
    __syncthreads();

    // phase 3: softmax over the 16 points of each head
    if (tid < 8) {
        float mx = -1e30f;
        for (int i = 0; i < 16; ++i) mx = fmaxf(mx, dsum[tid * 16 + i]);
        float sum = 0.f;
        for (int i = 0; i < 16; ++i) { float e = exp2f_fast((dsum[tid * 16 + i] - mx) * LOG2E); dsum[tid * 16 + i] = e; sum += e; }
        float inv = rcpf(sum);
        for (int i = 0; i < 16; ++i) dsum[tid * 16 + i] *= inv;
    }
    __syncthreads();

    // phase 4: att_res (bf16 into Acat)
    {
        const int h = tid >> 6, d = tid & 63;
        const int ch = d >> 3, e = d & 7;
        float s = 0.f;
#pragma unroll
        for (int p = 0; p < 16; ++p) {
            const int row = h * 16 + p;
            s += dsum[h * 16 + p] * bf2f(cf[row * 64 + ((ch ^ (row & 7)) * 8) + e]);
        }
        attdst[(size_t)b * 2048 + tid] = f2bf(s);
    }
}

// LSTM elementwise; optionally emits bf16 h into hbf (row stride 1024)
__global__ __launch_bounds__(256) void lstm_act(
    const float* __restrict__ g, const float* __restrict__ c_in,
    float* __restrict__ h_out, float* __restrict__ h_out2,
    unsigned short* __restrict__ hbf, float* __restrict__ c_out)
{
    const int idx = blockIdx.x * 256 + threadIdx.x;  // 0..524287
    const int m = idx >> 9, j = idx & 511;
    const float* gr = g + (size_t)m * 2048;
    const float gi = gr[j], gf = gr[512 + j], gg = gr[1024 + j], go = gr[1536 + j];
    const float c  = c_in[idx];
    const float c2 = sigf(gf) * c + sigf(gi) * tanhf_fast(gg);
    const float h2 = sigf(go) * tanhf_fast(c2);
    h_out[idx] = h2;
    if (h_out2) h_out2[idx] = h2;
    if (hbf) hbf[(size_t)m * 1024 + j] = f2bf(h2);
    c_out[idx] = c2;
}

extern "C" void kernel_launch(void* const* d_in, const int* in_sizes, int n_in,
                              void* d_out, int out_size, void* d_ws, size_t ws_size,
                              hipStream_t stream) {
    const float* xt     = (const float*)d_in[0];
    const float* h0     = (const float*)d_in[1];   // (2,1024,512)
    const float* c0     = (const float*)d_in[2];
    const float* query  = (const float*)d_in[3];   // (1,1024,512)
    const float* refp   = (const float*)d_in[4];   // (1,1024,4,1)
    const float* inflat = (const float*)d_in[5];   // (1,1920,512)
    const int*   shapes = (const int*)d_in[6];
    const int*   starts = (const int*)d_in[7];
    const float* Wv     = (const float*)d_in[9];   // (512,512) (K,N)
    const float* bv     = (const float*)d_in[10];
    const float* Woff   = (const float*)d_in[11];  // (1024,128) (K,N)
    const float* boff   = (const float*)d_in[12];
    const float* Wattw  = (const float*)d_in[13];  // (1024,128)
    const float* battw  = (const float*)d_in[14];
    const float* Wctx   = (const float*)d_in[15];  // (64,512)
    const float* bctx   = (const float*)d_in[16];
    const float* Wh2a   = (const float*)d_in[17];  // (512,512) (K,N)
    const float* bh2a   = (const float*)d_in[18];
    const float* walpha = (const float*)d_in[19];
    const float* Wih0   = (const float*)d_in[21];  // (2048,1536) (N,K)
    const float* Whh0   = (const float*)d_in[22];  // (2048,512)
    const float* Wih1   = (const float*)d_in[23];  // (2048,512)
    const float* Whh1   = (const float*)d_in[24];  // (2048,512)

    float* out = (float*)d_out;
    float* ws  = (float*)d_ws;

    // ws layout (f32 units), lifetime-overlapped; total 8585216 f32 = 34.4 MB
    float*          v     = ws;                                   // 983040
    float*          obat  = ws + 983040;                          // 1024x768 [off|aw|atth]
    unsigned short* Acat  = (unsigned short*)(ws + 1769472);      // 1024x2048 bf16
    unsigned short* Bcat0 = (unsigned short*)(ws + 2818048);      // 2048x2048 bf16
    float*          g     = ws + 4915200;                         // 2097152
    //   early-phase tenants of the g region (dead before gemm0 writes g):
    unsigned short* Ainf  = (unsigned short*)(ws + 4915200);      // 1920x512 bf16
    unsigned short* Wvt   = (unsigned short*)(ws + 5406720);      // 512x512 bf16
    unsigned short* Wcat  = (unsigned short*)(ws + 5537792);      // 768x1024 bf16 [Woff^T|Wattw^T|Wh2a^T pad0]
    unsigned short* Ahq   = (unsigned short*)(ws + 5931008);      // 1024x1024 bf16
    unsigned short* Wb    = (unsigned short*)(ws + 6455296);      // 512x64 bf16 (Wctx^T)
    float*          bcat  = ws + 6471680;                         // 768
    unsigned short* Ag1   = (unsigned short*)(ws + 7012352);      // 1024x1024 bf16
    unsigned short* Bcat1 = (unsigned short*)(ws + 7536640);      // 2048x1024 bf16

    const float* h00    = h0;
    const float* h_last = h0 + 524288;     // h0[1]
    float* h1  = out + 524288;             // h_new[0]
    float* c1  = out + 1572864;            // c_new[0]
    float* h2a = out;                      // first output
    float* h2b = out + 1048576;            // h_new[1]
    float* c2  = out + 2097152;            // c_new[1]

    // --- prep: converts (1 launch), memset pad, transposes (1 launch), biases ---
    { CvtJobs cj;
      cj.j[0]  = { xt,     Acat,          512,  2048, 512,  524288 };
      cj.j[1]  = { query,  Acat + 1024,   512,  2048, 512,  524288 };
      cj.j[2]  = { h00,    Acat + 1536,   512,  2048, 512,  524288 };
      cj.j[3]  = { h_last, Ahq,           512,  1024, 512,  524288 };
      cj.j[4]  = { query,  Ahq + 512,     512,  1024, 512,  524288 };
      cj.j[5]  = { h_last, Ag1 + 512,     512,  1024, 512,  524288 };
      cj.j[6]  = { Wih0,   Bcat0,         1536, 2048, 1536, 3145728 };
      cj.j[7]  = { Whh0,   Bcat0 + 1536,  512,  2048, 512,  1048576 };
      cj.j[8]  = { Wih1,   Bcat1,         512,  1024, 512,  1048576 };
      cj.j[9]  = { Whh1,   Bcat1 + 512,   512,  1024, 512,  1048576 };
      cj.j[10] = { inflat, Ainf,          512,  512,  512,  983040 };
      cvt_bf16<<<dim3(3072, 11), 256, 0, stream>>>(cj); }
    hipMemsetAsync(Wcat, 0, (size_t)768 * 1024 * 2, stream);   // zero K-pad for Wh2a rows
    { TJobs tj;
      tj.j[0] = { Wv,    Wvt,               512, 512,  512,  262144 };
      tj.j[1] = { Woff,  Wcat,              128, 1024, 1024, 131072 };
      tj.j[2] = { Wattw, Wcat + 128 * 1024, 128, 1024, 1024, 131072 };
      tj.j[3] = { Wh2a,  Wcat + 256 * 1024, 512, 1024, 512,  262144 };
      tj.j[4] = { Wctx,  Wb,                512, 64,   64,   32768 };
      tcvt_bf16<<<dim3(1024, 5), 256, 0, stream>>>(tj); }
    bias_cat3<<<1, 768, 0, stream>>>(boff, battw, bh2a, bcat);

    // --- GEMMs (bf16 MFMA) ---
    // value: v = inflat @ Wv + bv          (1920x512, K=512)  [LDS-staged]
    sgemm<<<dim3(4, 30), 256, 0, stream>>>(Ainf, 512, Wvt, 512, bv, v, 512, 512);
    // obat = [h_last|query] @ [Woff|Wattw|Wh2a pad] + [boff|battw|bh2a]  (1024x768, K=1024)
    mgemm<<<dim3(12, 16), 256, 0, stream>>>(Ahq, 1024, Wcat, 1024, bcat, obat, 768, 1024);

    // --- fused deformable sampling + context attention (writes Acat[:,512:1024]) ---
    fused_att<<<1024, 512, 0, stream>>>(v, obat, refp, shapes, starts,
                                        Wb, bctx, walpha, Acat + 512);

    // g0 = [xt|att_res|query|h0[0]] @ [Wih0|Whh0]^T    (1024x2048, K=2048)  [LDS-staged]
    sgemm<<<dim3(16, 16), 256, 0, stream>>>(Acat, 2048, Bcat0, 2048, nullptr, g, 2048, 2048);
    lstm_act<<<2048, 256, 0, stream>>>(g, c0, h1, nullptr, Ag1, c1);
    // g1 = [h1|h0[1]] @ [Wih1|Whh1]^T                  (1024x2048, K=1024)  [LDS-staged]
    sgemm<<<dim3(16, 16), 256, 0, stream>>>(Ag1, 1024, Bcat1, 1024, nullptr, g, 2048, 1024);
    lstm_act<<<2048, 256, 0, stream>>>(g, c0 + 524288, h2a, h2b, nullptr, c2);
}

// Round 8
// 148.746 us; speedup vs baseline: 1.3025x; 1.2552x over previous
//
#include <hip/hip_runtime.h>
#include <math.h>

// Problem constants (ShowAttendTellCore)
//   B=1024, D_MODEL=512, N_HEADS=8, D_HEAD=64, N_LEVELS=4, N_POINTS=4
//   T_TOTAL=1920, RNN=512, ENC=512, ATT_HID=512
// Output layout (f32): h2 (524288) | h1 | h2 | c1 | c2   (total 2621440)

typedef __attribute__((ext_vector_type(8))) short          s16x8;
typedef __attribute__((ext_vector_type(8))) unsigned short u16x8;
typedef __attribute__((ext_vector_type(4))) float          f32x4;

#define LOG2E  1.4426950408889634f
#define LOG2E2 2.8853900817779268f

__device__ __forceinline__ float rcpf(float x) { return __builtin_amdgcn_rcpf(x); }
__device__ __forceinline__ float exp2f_fast(float x) { return __builtin_amdgcn_exp2f(x); }
// sigmoid: 1/(1+2^(-x*log2e))   (~1ulp rcp; fine vs 7.4e-2 threshold)
__device__ __forceinline__ float sigf(float x) {
    return rcpf(1.0f + exp2f_fast(-x * LOG2E));
}
// tanh: 1 - 2*rcp(2^(2x*log2e)+1), clamped
__device__ __forceinline__ float tanhf_fast(float x) {
    const float xc = fminf(fmaxf(x, -15.0f), 15.0f);
    const float e2 = exp2f_fast(xc * LOG2E2);
    return 1.0f - 2.0f * rcpf(e2 + 1.0f);
}
__device__ __forceinline__ unsigned short f2bf(float f) {   // RNE f32->bf16
    unsigned u = __float_as_uint(f);
    u += 0x7FFF + ((u >> 16) & 1);
    return (unsigned short)(u >> 16);
}
__device__ __forceinline__ float bf2f(unsigned short h) {
    return __uint_as_float(((unsigned)h) << 16);
}
// async global->LDS, 16B per lane (lane i lands at firstlane_dst + i*16)
__device__ __forceinline__ void gld_lds16(const unsigned short* g, unsigned short* l) {
    __builtin_amdgcn_global_load_lds(
        (const __attribute__((address_space(1))) void*)g,
        (__attribute__((address_space(3))) void*)l, 16, 0, 0);
}

// ---------------- batched f32 -> bf16 strided converts (one launch) --------
struct CvtJob { const float* src; unsigned short* dst; int sld, dld, cols, total; };
struct CvtJobs { CvtJob j[11]; };
__global__ __launch_bounds__(256) void cvt_bf16(CvtJobs cj) {
    const CvtJob jb = cj.j[blockIdx.y];
    const int i = (blockIdx.x * 256 + threadIdx.x) * 4;
    if (i >= jb.total) return;
    const int r = i / jb.cols, c = i - r * jb.cols;
    const float4 v4 = *(const float4*)&jb.src[(size_t)r * jb.sld + c];
    ushort4 o;
    o.x = f2bf(v4.x); o.y = f2bf(v4.y); o.z = f2bf(v4.z); o.w = f2bf(v4.w);
    *(ushort4*)&jb.dst[(size_t)r * jb.dld + c] = o;
}

// transpose-convert: dst[n][k] = bf16(src[k][n]);  src is (K_, N_) row-major
struct TJob { const float* src; unsigned short* dst; int N_, dld, K_, total; };
struct TJobs { TJob j[5]; };
__global__ __launch_bounds__(256) void tcvt_bf16(TJobs tj) {
    const TJob jb = tj.j[blockIdx.y];
    const int i = blockIdx.x * 256 + threadIdx.x;
    if (i >= jb.total) return;
    const int n = i / jb.K_, k = i - n * jb.K_;
    jb.dst[(size_t)n * jb.dld + k] = f2bf(jb.src[(size_t)k * jb.N_ + n]);
}

// bcat = [boff(128) | battw(128) | bh2a(512)]
__global__ __launch_bounds__(768) void bias_cat3(const float* __restrict__ a,
                                                 const float* __restrict__ b,
                                                 const float* __restrict__ c,
                                                 float* __restrict__ dst) {
    const int t = threadIdx.x;
    dst[t] = (t < 128) ? a[t] : (t < 256 ? b[t - 128] : c[t - 256]);
}

// ---------------- LDS-staged bf16 MFMA GEMM (2-phase double-buffer) --------
// C(MxN f32) = A(MxK bf16 rm, lda) @ B^T (B NxK bf16 rm, ldb) + bias
// BM=64 BN=128 BK=32; grid=(N/128, M/64); 256 thr = 4 waves (2x2), wave=32x64.
__global__ __launch_bounds__(256) void sgemm(
    const unsigned short* __restrict__ A, int lda,
    const unsigned short* __restrict__ B, int ldb,
    const float* __restrict__ bias, float* __restrict__ C, int ldc, int K)
{
    __shared__ unsigned short As[2][64 * 32];
    __shared__ unsigned short Bs[2][128 * 32];

    const int tid = threadIdx.x;
    const int w = tid >> 6, lane = tid & 63;
    const int wr = w >> 1, wc = w & 1;
    const int lr = lane & 15, lg = lane >> 4;
    const int bm = blockIdx.y, bn = blockIdx.x;

    const int srow = tid >> 2, sk = (tid & 3) << 3;
    const unsigned short* Ag  = A + (size_t)(bm * 64 + srow) * lda + sk;
    const unsigned short* Bg0 = B + (size_t)(bn * 128 + srow) * ldb + sk;
    const unsigned short* Bg1 = B + (size_t)(bn * 128 + 64 + srow) * ldb + sk;

    f32x4 acc[2][4];
#pragma unroll
    for (int mt = 0; mt < 2; ++mt)
#pragma unroll
        for (int nt = 0; nt < 4; ++nt) acc[mt][nt] = (f32x4){0.f, 0.f, 0.f, 0.f};

    const int nsteps = K >> 5;
    int cur = 0;
    gld_lds16(Ag,  &As[0][tid * 8]);
    gld_lds16(Bg0, &Bs[0][tid * 8]);
    gld_lds16(Bg1, &Bs[0][2048 + tid * 8]);
    asm volatile("s_waitcnt vmcnt(0)" ::: "memory");
    __syncthreads();

    for (int t = 0; t < nsteps; ++t) {
        const int k1 = (t + 1) << 5;
        if (t + 1 < nsteps) {
            gld_lds16(Ag + k1,  &As[cur ^ 1][tid * 8]);
            gld_lds16(Bg0 + k1, &Bs[cur ^ 1][tid * 8]);
            gld_lds16(Bg1 + k1, &Bs[cur ^ 1][2048 + tid * 8]);
        }
        const unsigned short* Ab = &As[cur][0];
        const unsigned short* Bb = &Bs[cur][0];
        s16x8 a[2], bfr[4];
#pragma unroll
        for (int mt = 0; mt < 2; ++mt)
            a[mt] = *(const s16x8*)&Ab[(wr * 32 + mt * 16 + lr) * 32 + lg * 8];
#pragma unroll
        for (int nt = 0; nt < 4; ++nt)
            bfr[nt] = *(const s16x8*)&Bb[(wc * 64 + nt * 16 + lr) * 32 + lg * 8];
#pragma unroll
        for (int mt = 0; mt < 2; ++mt)
#pragma unroll
            for (int nt = 0; nt < 4; ++nt)
                acc[mt][nt] = __builtin_amdgcn_mfma_f32_16x16x32_bf16(
                    a[mt], bfr[nt], acc[mt][nt], 0, 0, 0);
        asm volatile("s_waitcnt vmcnt(0)" ::: "memory");
        __syncthreads();
        cur ^= 1;
    }
#pragma unroll
    for (int nt = 0; nt < 4; ++nt) {
        const int col = bn * 128 + wc * 64 + nt * 16 + lr;
        const float bb = bias ? bias[col] : 0.0f;
#pragma unroll
        for (int mt = 0; mt < 2; ++mt) {
            const int rbase = bm * 64 + wr * 32 + mt * 16 + lg * 4;
#pragma unroll
            for (int r = 0; r < 4; ++r)
                C[(size_t)(rbase + r) * ldc + col] = acc[mt][nt][r] + bb;
        }
    }
}

// ---------------- direct-global bf16 MFMA GEMM (small GEMMs only) ----------
__global__ __launch_bounds__(256) void mgemm(
    const unsigned short* __restrict__ A, int lda,
    const unsigned short* __restrict__ B, int ldb,
    const float* __restrict__ bias, float* __restrict__ C, int ldc, int K)
{
    const int tid = threadIdx.x;
    const int w = tid >> 6, lane = tid & 63;
    const int wm = w >> 1, wn = w & 1;
    const int lr = lane & 15, lg = lane >> 4;
    const int row0 = blockIdx.y * 64 + wm * 32;
    const int col0 = blockIdx.x * 64 + wn * 32;

    const unsigned short* Ap = A + (size_t)(row0 + lr) * lda + lg * 8;
    const unsigned short* Bp = B + (size_t)(col0 + lr) * ldb + lg * 8;

    f32x4 acc[2][2];
#pragma unroll
    for (int mt = 0; mt < 2; ++mt)
#pragma unroll
        for (int nt = 0; nt < 2; ++nt) acc[mt][nt] = (f32x4){0.f, 0.f, 0.f, 0.f};

    for (int k0 = 0; k0 < K; k0 += 64) {
        s16x8 a[2][2], bf[2][2];
#pragma unroll
        for (int mt = 0; mt < 2; ++mt)
#pragma unroll
            for (int u = 0; u < 2; ++u)
                a[mt][u] = *(const s16x8*)&Ap[(size_t)mt * 16 * lda + k0 + u * 32];
#pragma unroll
        for (int nt = 0; nt < 2; ++nt)
#pragma unroll
            for (int u = 0; u < 2; ++u)
                bf[nt][u] = *(const s16x8*)&Bp[(size_t)nt * 16 * ldb + k0 + u * 32];
#pragma unroll
        for (int u = 0; u < 2; ++u)
#pragma unroll
            for (int mt = 0; mt < 2; ++mt)
#pragma unroll
                for (int nt = 0; nt < 2; ++nt)
                    acc[mt][nt] = __builtin_amdgcn_mfma_f32_16x16x32_bf16(
                        a[mt][u], bf[nt][u], acc[mt][nt], 0, 0, 0);
    }
#pragma unroll
    for (int nt = 0; nt < 2; ++nt) {
        const int col = col0 + nt * 16 + lr;
        const float bb = bias ? bias[col] : 0.0f;
#pragma unroll
        for (int mt = 0; mt < 2; ++mt) {
            const int rbase = row0 + mt * 16 + lg * 4;
#pragma unroll
            for (int r = 0; r < 4; ++r)
                C[(size_t)(rbase + r) * ldc + col] = acc[mt][nt][r] + bb;
        }
    }
}

// ---------------- fused deformable sampling + context attention ------------
// obat (B,768) = [off(128) | aw_raw(128) | atth(512)]  (biases included)
// R5-proven structure. launch_bounds min-waves relaxed to 2 (allocator cap 256
// VGPR) and nt loop pinned non-unrolled: both guard against the R6/R7 scratch
// spill (132 MB/dispatch WRITE_SIZE from ~64 f32/thread spilled).
__global__ __launch_bounds__(512, 2) void fused_att(
    const float* __restrict__ v,       // (1920, 512)
    const float* __restrict__ obat,    // (B, 768)
    const float* __restrict__ refp,    // (B, 4)
    const int*   __restrict__ shapes,  // (4,)
    const int*   __restrict__ starts,  // (4,)
    const unsigned short* __restrict__ Wb,  // (512, 64) bf16, = Wctx^T
    const float* __restrict__ bctx,    // (512,)
    const float* __restrict__ walpha,  // (512,)
    unsigned short* __restrict__ attdst)    // bf16, row stride 2048
{
    __shared__ unsigned short cf[128 * 64];   // 16 KB, XOR chunk-swizzled
    __shared__ float ba[512];                 // bctx + atth[b]
    __shared__ float wal[512];
    __shared__ float awb[128];
    __shared__ float dsum[128];
    __shared__ float dots4[4][128];

    const int b   = blockIdx.x;
    const int tid = threadIdx.x;

    // phase 0: attention-weight softmax (16 per head)
    if (tid < 128) awb[tid] = obat[b * 768 + 128 + tid];
    __syncthreads();
    if (tid < 8) {
        float mx = -1e30f;
        for (int i = 0; i < 16; ++i) mx = fmaxf(mx, awb[tid * 16 + i]);
        float sum = 0.f;
        for (int i = 0; i < 16; ++i) { float e = exp2f_fast((awb[tid * 16 + i] - mx) * LOG2E); awb[tid * 16 + i] = e; sum += e; }
        float inv = rcpf(sum);
        for (int i = 0; i < 16; ++i) awb[tid * 16 + i] *= inv;
    }
    __syncthreads();

    // phase 1: bilinear sampling -> cf[p][d] = bf16(samp[d] * aw[p]); stage ba/wal
    ba[tid]  = bctx[tid] + obat[b * 768 + 256 + tid];
    wal[tid] = walpha[tid];
    {
        const int pg  = tid >> 2;
        const int sub = tid & 3;
        const int d0  = sub * 16;
        const int h   = pg >> 4;
        const int l   = (pg & 15) >> 2;
        const int Tlen = shapes[l];
        const int st   = starts[l];
        const float T  = (float)Tlen;
        const float refv = refp[b * 4 + l];
        const float offv = obat[b * 768 + pg];
        const float awv  = awb[pg];
        const float x   = (refv + offv * rcpf(T)) * T - 0.5f;  // exact: T is 2^k
        const float x0f = floorf(x);
        const float w1  = x - x0f;
        const int   x0  = (int)x0f;
        const float w0s = (x0 >= 0 && x0 < Tlen) ? (1.0f - w1) : 0.0f;
        const float w1s = (x0 + 1 >= 0 && x0 + 1 < Tlen) ? w1 : 0.0f;
        const int i0 = (min(max(x0, 0), Tlen - 1) + st) * 512 + h * 64;
        const int i1 = (min(max(x0 + 1, 0), Tlen - 1) + st) * 512 + h * 64;
        u16x8 o0, o1;
#pragma unroll
        for (int q = 0; q < 4; ++q) {
            const float4 a  = *(const float4*)&v[i0 + d0 + q * 4];
            const float4 bq = *(const float4*)&v[i1 + d0 + q * 4];
            unsigned short e0 = f2bf((a.x * w0s + bq.x * w1s) * awv);
            unsigned short e1 = f2bf((a.y * w0s + bq.y * w1s) * awv);
            unsigned short e2 = f2bf((a.z * w0s + bq.z * w1s) * awv);
            unsigned short e3 = f2bf((a.w * w0s + bq.w * w1s) * awv);
            if (q == 0) { o0[0] = e0; o0[1] = e1; o0[2] = e2; o0[3] = e3; }
            if (q == 1) { o0[4] = e0; o0[5] = e1; o0[6] = e2; o0[7] = e3; }
            if (q == 2) { o1[0] = e0; o1[1] = e1; o1[2] = e2; o1[3] = e3; }
            if (q == 3) { o1[4] = e0; o1[5] = e1; o1[6] = e2; o1[7] = e3; }
        }
        const int c0 = (sub * 2)     ^ (pg & 7);
        const int c1 = (sub * 2 + 1) ^ (pg & 7);
        *(u16x8*)&cf[pg * 64 + c0 * 8] = o0;
        *(u16x8*)&cf[pg * 64 + c1 * 8] = o1;
    }
    __syncthreads();

    // phase 2: dots[p] = sum_j tanh((cf@Wctx)[p][j] + ba[j]) * wal[j]  via MFMA
    {
        const int w    = tid >> 6, lane = tid & 63;
        const int wm   = w >> 2, wn = w & 3;
        const int lr   = lane & 15, lg = lane >> 4;

        s16x8 afrag[4][2];
#pragma unroll
        for (int mt = 0; mt < 4; ++mt) {
            const int row = wm * 64 + mt * 16 + lr;
#pragma unroll
            for (int ks = 0; ks < 2; ++ks) {
                const int ch = (ks * 4 + lg) ^ (row & 7);
                afrag[mt][ks] = *(const s16x8*)&cf[row * 64 + ch * 8];
            }
        }
        f32x4 part[4];
#pragma unroll
        for (int mt = 0; mt < 4; ++mt) part[mt] = (f32x4){0.f, 0.f, 0.f, 0.f};

#pragma clang loop unroll(disable)
        for (int nt = 0; nt < 8; ++nt) {
            const int ct  = wn * 8 + nt;
            const int col = ct * 16 + lr;
            const s16x8 b0 = *(const s16x8*)&Wb[col * 64 + lg * 8];
            const s16x8 b1 = *(const s16x8*)&Wb[col * 64 + 32 + lg * 8];
            const float bav = ba[col], wav = wal[col];
#pragma unroll
            for (int mt = 0; mt < 4; ++mt) {
                f32x4 acc = {0.f, 0.f, 0.f, 0.f};
                acc = __builtin_amdgcn_mfma_f32_16x16x32_bf16(afrag[mt][0], b0, acc, 0, 0, 0);
                acc = __builtin_amdgcn_mfma_f32_16x16x32_bf16(afrag[mt][1], b1, acc, 0, 0, 0);
#pragma unroll
                for (int r = 0; r < 4; ++r)
                    part[mt][r] += tanhf_fast(acc[r] + bav) * wav;
            }
        }
#pragma unroll
        for (int mt = 0; mt < 4; ++mt) {
#pragma unroll
            for (int r = 0; r < 4; ++r) {
                float s = part[mt][r];
                s += __shfl_xor(s, 1); s += __shfl_xor(s, 2);
                s += __shfl_xor(s, 4); s += __shfl_xor(s, 8);
                if (lr == 0) dots4[wn][wm * 64 + mt * 16 + lg * 4 + r] = s;
            }
        }
    }
    __syncthreads();
    if (tid < 128)
        dsum[tid] = dots4[0][tid] + dots4[1][tid] + dots4[2][tid] + dots4[3][tid];
    __syncthreads();

    // phase 3: softmax over the 16 points of each head
    if (tid < 8) {
        float mx = -1e30f;
        for (int i = 0; i < 16; ++i) mx = fmaxf(mx, dsum[tid * 16 + i]);
        float sum = 0.f;
        for (int i = 0; i < 16; ++i) { float e = exp2f_fast((dsum[tid * 16 + i] - mx) * LOG2E); dsum[tid * 16 + i] = e; sum += e; }
        float inv = rcpf(sum);
        for (int i = 0; i < 16; ++i) dsum[tid * 16 + i] *= inv;
    }
    __syncthreads();

    // phase 4: att_res (bf16 into Acat)
    {
        const int h = tid >> 6, d = tid & 63;
        const int ch = d >> 3, e = d & 7;
        float s = 0.f;
#pragma unroll
        for (int p = 0; p < 16; ++p) {
            const int row = h * 16 + p;
            s += dsum[h * 16 + p] * bf2f(cf[row * 64 + ((ch ^ (row & 7)) * 8) + e]);
        }
        attdst[(size_t)b * 2048 + tid] = f2bf(s);
    }
}

// LSTM elementwise; optionally emits bf16 h into hbf (row stride 1024)
__global__ __launch_bounds__(256) void lstm_act(
    const float* __restrict__ g, const float* __restrict__ c_in,
    float* __restrict__ h_out, float* __restrict__ h_out2,
    unsigned short* __restrict__ hbf, float* __restrict__ c_out)
{
    const int idx = blockIdx.x * 256 + threadIdx.x;  // 0..524287
    const int m = idx >> 9, j = idx & 511;
    const float* gr = g + (size_t)m * 2048;
    const float gi = gr[j], gf = gr[512 + j], gg = gr[1024 + j], go = gr[1536 + j];
    const float c  = c_in[idx];
    const float c2 = sigf(gf) * c + sigf(gi) * tanhf_fast(gg);
    const float h2 = sigf(go) * tanhf_fast(c2);
    h_out[idx] = h2;
    if (h_out2) h_out2[idx] = h2;
    if (hbf) hbf[(size_t)m * 1024 + j] = f2bf(h2);
    c_out[idx] = c2;
}

extern "C" void kernel_launch(void* const* d_in, const int* in_sizes, int n_in,
                              void* d_out, int out_size, void* d_ws, size_t ws_size,
                              hipStream_t stream) {
    const float* xt     = (const float*)d_in[0];
    const float* h0     = (const float*)d_in[1];   // (2,1024,512)
    const float* c0     = (const float*)d_in[2];
    const float* query  = (const float*)d_in[3];   // (1,1024,512)
    const float* refp   = (const float*)d_in[4];   // (1,1024,4,1)
    const float* inflat = (const float*)d_in[5];   // (1,1920,512)
    const int*   shapes = (const int*)d_in[6];
    const int*   starts = (const int*)d_in[7];
    const float* Wv     = (const float*)d_in[9];   // (512,512) (K,N)
    const float* bv     = (const float*)d_in[10];
    const float* Woff   = (const float*)d_in[11];  // (1024,128) (K,N)
    const float* boff   = (const float*)d_in[12];
    const float* Wattw  = (const float*)d_in[13];  // (1024,128)
    const float* battw  = (const float*)d_in[14];
    const float* Wctx   = (const float*)d_in[15];  // (64,512)
    const float* bctx   = (const float*)d_in[16];
    const float* Wh2a   = (const float*)d_in[17];  // (512,512) (K,N)
    const float* bh2a   = (const float*)d_in[18];
    const float* walpha = (const float*)d_in[19];
    const float* Wih0   = (const float*)d_in[21];  // (2048,1536) (N,K)
    const float* Whh0   = (const float*)d_in[22];  // (2048,512)
    const float* Wih1   = (const float*)d_in[23];  // (2048,512)
    const float* Whh1   = (const float*)d_in[24];  // (2048,512)

    float* out = (float*)d_out;
    float* ws  = (float*)d_ws;

    // ws layout (f32 units), lifetime-overlapped; total 8585216 f32 = 34.4 MB
    float*          v     = ws;                                   // 983040
    float*          obat  = ws + 983040;                          // 1024x768 [off|aw|atth]
    unsigned short* Acat  = (unsigned short*)(ws + 1769472);      // 1024x2048 bf16
    unsigned short* Bcat0 = (unsigned short*)(ws + 2818048);      // 2048x2048 bf16
    float*          g     = ws + 4915200;                         // 2097152
    //   early-phase tenants of the g region (dead before gemm0 writes g):
    unsigned short* Ainf  = (unsigned short*)(ws + 4915200);      // 1920x512 bf16
    unsigned short* Wvt   = (unsigned short*)(ws + 5406720);      // 512x512 bf16
    unsigned short* Wcat  = (unsigned short*)(ws + 5537792);      // 768x1024 bf16 [Woff^T|Wattw^T|Wh2a^T pad0]
    unsigned short* Ahq   = (unsigned short*)(ws + 5931008);      // 1024x1024 bf16
    unsigned short* Wb    = (unsigned short*)(ws + 6455296);      // 512x64 bf16 (Wctx^T)
    float*          bcat  = ws + 6471680;                         // 768
    unsigned short* Ag1   = (unsigned short*)(ws + 7012352);      // 1024x1024 bf16
    unsigned short* Bcat1 = (unsigned short*)(ws + 7536640);      // 2048x1024 bf16

    const float* h00    = h0;
    const float* h_last = h0 + 524288;     // h0[1]
    float* h1  = out + 524288;             // h_new[0]
    float* c1  = out + 1572864;            // c_new[0]
    float* h2a = out;                      // first output
    float* h2b = out + 1048576;            // h_new[1]
    float* c2  = out + 2097152;            // c_new[1]

    // --- prep: converts (1 launch), memset pad, transposes (1 launch), biases ---
    { CvtJobs cj;
      cj.j[0]  = { xt,     Acat,          512,  2048, 512,  524288 };
      cj.j[1]  = { query,  Acat + 1024,   512,  2048, 512,  524288 };
      cj.j[2]  = { h00,    Acat + 1536,   512,  2048, 512,  524288 };
      cj.j[3]  = { h_last, Ahq,           512,  1024, 512,  524288 };
      cj.j[4]  = { query,  Ahq + 512,     512,  1024, 512,  524288 };
      cj.j[5]  = { h_last, Ag1 + 512,     512,  1024, 512,  524288 };
      cj.j[6]  = { Wih0,   Bcat0,         1536, 2048, 1536, 3145728 };
      cj.j[7]  = { Whh0,   Bcat0 + 1536,  512,  2048, 512,  1048576 };
      cj.j[8]  = { Wih1,   Bcat1,         512,  1024, 512,  1048576 };
      cj.j[9]  = { Whh1,   Bcat1 + 512,   512,  1024, 512,  1048576 };
      cj.j[10] = { inflat, Ainf,          512,  512,  512,  983040 };
      cvt_bf16<<<dim3(3072, 11), 256, 0, stream>>>(cj); }
    hipMemsetAsync(Wcat, 0, (size_t)768 * 1024 * 2, stream);   // zero K-pad for Wh2a rows
    { TJobs tj;
      tj.j[0] = { Wv,    Wvt,               512, 512,  512,  262144 };
      tj.j[1] = { Woff,  Wcat,              128, 1024, 1024, 131072 };
      tj.j[2] = { Wattw, Wcat + 128 * 1024, 128, 1024, 1024, 131072 };
      tj.j[3] = { Wh2a,  Wcat + 256 * 1024, 512, 1024, 512,  262144 };
      tj.j[4] = { Wctx,  Wb,                512, 64,   64,   32768 };
      tcvt_bf16<<<dim3(1024, 5), 256, 0, stream>>>(tj); }
    bias_cat3<<<1, 768, 0, stream>>>(boff, battw, bh2a, bcat);

    // --- GEMMs (bf16 MFMA) ---
    // value: v = inflat @ Wv + bv          (1920x512, K=512)  [LDS-staged]
    sgemm<<<dim3(4, 30), 256, 0, stream>>>(Ainf, 512, Wvt, 512, bv, v, 512, 512);
    // obat = [h_last|query] @ [Woff|Wattw|Wh2a pad] + [boff|battw|bh2a]  (1024x768, K=1024)
    mgemm<<<dim3(12, 16), 256, 0, stream>>>(Ahq, 1024, Wcat, 1024, bcat, obat, 768, 1024);

    // --- fused deformable sampling + context attention (writes Acat[:,512:1024]) ---
    fused_att<<<1024, 512, 0, stream>>>(v, obat, refp, shapes, starts,
                                        Wb, bctx, walpha, Acat + 512);

    // g0 = [xt|att_res|query|h0[0]] @ [Wih0|Whh0]^T    (1024x2048, K=2048)  [LDS-staged]
    sgemm<<<dim3(16, 16), 256, 0, stream>>>(Acat, 2048, Bcat0, 2048, nullptr, g, 2048, 2048);
    lstm_act<<<2048, 256, 0, stream>>>(g, c0, h1, nullptr, Ag1, c1);
    // g1 = [h1|h0[1]] @ [Wih1|Whh1]^T                  (1024x2048, K=1024)  [LDS-staged]
    sgemm<<<dim3(16, 16), 256, 0, stream>>>(Ag1, 1024, Bcat1, 1024, nullptr, g, 2048, 1024);
    lstm_act<<<2048, 256, 0, stream>>>(g, c0 + 524288, h2a, h2b, nullptr, c2);
}

// Round 9
// 146.423 us; speedup vs baseline: 1.3231x; 1.0159x over previous
//
#include <hip/hip_runtime.h>
#include <math.h>

// Problem constants (ShowAttendTellCore)
//   B=1024, D_MODEL=512, N_HEADS=8, D_HEAD=64, N_LEVELS=4, N_POINTS=4
//   T_TOTAL=1920, RNN=512, ENC=512, ATT_HID=512
// Output layout (f32): h2 (524288) | h1 | h2 | c1 | c2   (total 2621440)

typedef __attribute__((ext_vector_type(8))) short          s16x8;
typedef __attribute__((ext_vector_type(8))) unsigned short u16x8;
typedef __attribute__((ext_vector_type(4))) float          f32x4;

#define LOG2E  1.4426950408889634f
#define LOG2E2 2.8853900817779268f

__device__ __forceinline__ float rcpf(float x) { return __builtin_amdgcn_rcpf(x); }
__device__ __forceinline__ float exp2f_fast(float x) { return __builtin_amdgcn_exp2f(x); }
// sigmoid: 1/(1+2^(-x*log2e))   (~1ulp rcp; fine vs 7.4e-2 threshold)
__device__ __forceinline__ float sigf(float x) {
    return rcpf(1.0f + exp2f_fast(-x * LOG2E));
}
// tanh: 1 - 2*rcp(2^(2x*log2e)+1), clamped
__device__ __forceinline__ float tanhf_fast(float x) {
    const float xc = fminf(fmaxf(x, -15.0f), 15.0f);
    const float e2 = exp2f_fast(xc * LOG2E2);
    return 1.0f - 2.0f * rcpf(e2 + 1.0f);
}
__device__ __forceinline__ unsigned short f2bf(float f) {   // RNE f32->bf16
    unsigned u = __float_as_uint(f);
    u += 0x7FFF + ((u >> 16) & 1);
    return (unsigned short)(u >> 16);
}
__device__ __forceinline__ float bf2f(unsigned short h) {
    return __uint_as_float(((unsigned)h) << 16);
}
// async global->LDS, 16B per lane (lane i lands at firstlane_dst + i*16)
__device__ __forceinline__ void gld_lds16(const unsigned short* g, unsigned short* l) {
    __builtin_amdgcn_global_load_lds(
        (const __attribute__((address_space(1))) void*)g,
        (__attribute__((address_space(3))) void*)l, 16, 0, 0);
}

// ---------------- batched f32 -> bf16 strided converts (one launch) --------
struct CvtJob { const float* src; unsigned short* dst; int sld, dld, cols, total; };
struct CvtJobs { CvtJob j[11]; };
__global__ __launch_bounds__(256) void cvt_bf16(CvtJobs cj) {
    const CvtJob jb = cj.j[blockIdx.y];
    const int i = (blockIdx.x * 256 + threadIdx.x) * 4;
    if (i >= jb.total) return;
    const int r = i / jb.cols, c = i - r * jb.cols;
    const float4 v4 = *(const float4*)&jb.src[(size_t)r * jb.sld + c];
    ushort4 o;
    o.x = f2bf(v4.x); o.y = f2bf(v4.y); o.z = f2bf(v4.z); o.w = f2bf(v4.w);
    *(ushort4*)&jb.dst[(size_t)r * jb.dld + c] = o;
}

// transpose-convert: dst[n][k] = bf16(src[k][n]);  src is (K_, N_) row-major.
// src == nullptr -> zero-fill job (replaces the pathological runtime memset:
// R8 profile showed fillBufferAligned at ~40 us/replay for a 1.5 MB pad).
struct TJob { const float* src; unsigned short* dst; int N_, dld, K_, total; };
struct TJobs { TJob j[6]; };
__global__ __launch_bounds__(256) void tcvt_bf16(TJobs tj) {
    const TJob jb = tj.j[blockIdx.y];
    const int i = blockIdx.x * 256 + threadIdx.x;
    if (i >= jb.total) return;
    const int n = i / jb.K_, k = i - n * jb.K_;
    jb.dst[(size_t)n * jb.dld + k] =
        jb.src ? f2bf(jb.src[(size_t)k * jb.N_ + n]) : (unsigned short)0;
}

// bcat = [boff(128) | battw(128) | bh2a(512)]
__global__ __launch_bounds__(768) void bias_cat3(const float* __restrict__ a,
                                                 const float* __restrict__ b,
                                                 const float* __restrict__ c,
                                                 float* __restrict__ dst) {
    const int t = threadIdx.x;
    dst[t] = (t < 128) ? a[t] : (t < 256 ? b[t - 128] : c[t - 256]);
}

// ---------------- LDS-staged bf16 MFMA GEMM (2-phase double-buffer) --------
// C(MxN f32) = A(MxK bf16 rm, lda) @ B^T (B NxK bf16 rm, ldb) + bias
// BM=64 BN=128 BK=32; grid=(N/128, M/64); 256 thr = 4 waves (2x2), wave=32x64.
__global__ __launch_bounds__(256) void sgemm(
    const unsigned short* __restrict__ A, int lda,
    const unsigned short* __restrict__ B, int ldb,
    const float* __restrict__ bias, float* __restrict__ C, int ldc, int K)
{
    __shared__ unsigned short As[2][64 * 32];
    __shared__ unsigned short Bs[2][128 * 32];

    const int tid = threadIdx.x;
    const int w = tid >> 6, lane = tid & 63;
    const int wr = w >> 1, wc = w & 1;
    const int lr = lane & 15, lg = lane >> 4;
    const int bm = blockIdx.y, bn = blockIdx.x;

    const int srow = tid >> 2, sk = (tid & 3) << 3;
    const unsigned short* Ag  = A + (size_t)(bm * 64 + srow) * lda + sk;
    const unsigned short* Bg0 = B + (size_t)(bn * 128 + srow) * ldb + sk;
    const unsigned short* Bg1 = B + (size_t)(bn * 128 + 64 + srow) * ldb + sk;

    f32x4 acc[2][4];
#pragma unroll
    for (int mt = 0; mt < 2; ++mt)
#pragma unroll
        for (int nt = 0; nt < 4; ++nt) acc[mt][nt] = (f32x4){0.f, 0.f, 0.f, 0.f};

    const int nsteps = K >> 5;
    int cur = 0;
    gld_lds16(Ag,  &As[0][tid * 8]);
    gld_lds16(Bg0, &Bs[0][tid * 8]);
    gld_lds16(Bg1, &Bs[0][2048 + tid * 8]);
    asm volatile("s_waitcnt vmcnt(0)" ::: "memory");
    __syncthreads();

    for (int t = 0; t < nsteps; ++t) {
        const int k1 = (t + 1) << 5;
        if (t + 1 < nsteps) {
            gld_lds16(Ag + k1,  &As[cur ^ 1][tid * 8]);
            gld_lds16(Bg0 + k1, &Bs[cur ^ 1][tid * 8]);
            gld_lds16(Bg1 + k1, &Bs[cur ^ 1][2048 + tid * 8]);
        }
        const unsigned short* Ab = &As[cur][0];
        const unsigned short* Bb = &Bs[cur][0];
        s16x8 a[2], bfr[4];
#pragma unroll
        for (int mt = 0; mt < 2; ++mt)
            a[mt] = *(const s16x8*)&Ab[(wr * 32 + mt * 16 + lr) * 32 + lg * 8];
#pragma unroll
        for (int nt = 0; nt < 4; ++nt)
            bfr[nt] = *(const s16x8*)&Bb[(wc * 64 + nt * 16 + lr) * 32 + lg * 8];
#pragma unroll
        for (int mt = 0; mt < 2; ++mt)
#pragma unroll
            for (int nt = 0; nt < 4; ++nt)
                acc[mt][nt] = __builtin_amdgcn_mfma_f32_16x16x32_bf16(
                    a[mt], bfr[nt], acc[mt][nt], 0, 0, 0);
        asm volatile("s_waitcnt vmcnt(0)" ::: "memory");
        __syncthreads();
        cur ^= 1;
    }
#pragma unroll
    for (int nt = 0; nt < 4; ++nt) {
        const int col = bn * 128 + wc * 64 + nt * 16 + lr;
        const float bb = bias ? bias[col] : 0.0f;
#pragma unroll
        for (int mt = 0; mt < 2; ++mt) {
            const int rbase = bm * 64 + wr * 32 + mt * 16 + lg * 4;
#pragma unroll
            for (int r = 0; r < 4; ++r)
                C[(size_t)(rbase + r) * ldc + col] = acc[mt][nt][r] + bb;
        }
    }
}

// ---------------- direct-global bf16 MFMA GEMM (small GEMMs only) ----------
__global__ __launch_bounds__(256) void mgemm(
    const unsigned short* __restrict__ A, int lda,
    const unsigned short* __restrict__ B, int ldb,
    const float* __restrict__ bias, float* __restrict__ C, int ldc, int K)
{
    const int tid = threadIdx.x;
    const int w = tid >> 6, lane = tid & 63;
    const int wm = w >> 1, wn = w & 1;
    const int lr = lane & 15, lg = lane >> 4;
    const int row0 = blockIdx.y * 64 + wm * 32;
    const int col0 = blockIdx.x * 64 + wn * 32;

    const unsigned short* Ap = A + (size_t)(row0 + lr) * lda + lg * 8;
    const unsigned short* Bp = B + (size_t)(col0 + lr) * ldb + lg * 8;

    f32x4 acc[2][2];
#pragma unroll
    for (int mt = 0; mt < 2; ++mt)
#pragma unroll
        for (int nt = 0; nt < 2; ++nt) acc[mt][nt] = (f32x4){0.f, 0.f, 0.f, 0.f};

    for (int k0 = 0; k0 < K; k0 += 64) {
        s16x8 a[2][2], bf[2][2];
#pragma unroll
        for (int mt = 0; mt < 2; ++mt)
#pragma unroll
            for (int u = 0; u < 2; ++u)
                a[mt][u] = *(const s16x8*)&Ap[(size_t)mt * 16 * lda + k0 + u * 32];
#pragma unroll
        for (int nt = 0; nt < 2; ++nt)
#pragma unroll
            for (int u = 0; u < 2; ++u)
                bf[nt][u] = *(const s16x8*)&Bp[(size_t)nt * 16 * ldb + k0 + u * 32];
#pragma unroll
        for (int u = 0; u < 2; ++u)
#pragma unroll
            for (int mt = 0; mt < 2; ++mt)
#pragma unroll
                for (int nt = 0; nt < 2; ++nt)
                    acc[mt][nt] = __builtin_amdgcn_mfma_f32_16x16x32_bf16(
                        a[mt][u], bf[nt][u], acc[mt][nt], 0, 0, 0);
    }
#pragma unroll
    for (int nt = 0; nt < 2; ++nt) {
        const int col = col0 + nt * 16 + lr;
        const float bb = bias ? bias[col] : 0.0f;
#pragma unroll
        for (int mt = 0; mt < 2; ++mt) {
            const int rbase = row0 + mt * 16 + lg * 4;
#pragma unroll
            for (int r = 0; r < 4; ++r)
                C[(size_t)(rbase + r) * ldc + col] = acc[mt][nt][r] + bb;
        }
    }
}

// ---------------- fused deformable sampling + context attention ------------
// obat (B,768) = [off(128) | aw_raw(128) | atth(512)]  (biases included)
// R5-proven structure. launch_bounds min-waves relaxed to 2 (allocator cap 256
// VGPR) and nt loop pinned non-unrolled: both guard against the R6/R7 scratch
// spill (132 MB/dispatch WRITE_SIZE from ~64 f32/thread spilled).
__global__ __launch_bounds__(512, 2) void fused_att(
    const float* __restrict__ v,       // (1920, 512)
    const float* __restrict__ obat,    // (B, 768)
    const float* __restrict__ refp,    // (B, 4)
    const int*   __restrict__ shapes,  // (4,)
    const int*   __restrict__ starts,  // (4,)
    const unsigned short* __restrict__ Wb,  // (512, 64) bf16, = Wctx^T
    const float* __restrict__ bctx,    // (512,)
    const float* __restrict__ walpha,  // (512,)
    unsigned short* __restrict__ attdst)    // bf16, row stride 2048
{
    __shared__ unsigned short cf[128 * 64];   // 16 KB, XOR chunk-swizzled
    __shared__ float ba[512];                 // bctx + atth[b]
    __shared__ float wal[512];
    __shared__ float awb[128];
    __shared__ float dsum[128];
    __shared__ float dots4[4][128];

    const int b   = blockIdx.x;
    const int tid = threadIdx.x;

    // phase 0: attention-weight softmax (16 per head)
    if (tid < 128) awb[tid] = obat[b * 768 + 128 + tid];
    __syncthreads();
    if (tid < 8) {
        float mx = -1e30f;
        for (int i = 0; i < 16; ++i) mx = fmaxf(mx, awb[tid * 16 + i]);
        float sum = 0.f;
        for (int i = 0; i < 16; ++i) { float e = exp2f_fast((awb[tid * 16 + i] - mx) * LOG2E); awb[tid * 16 + i] = e; sum += e; }
        float inv = rcpf(sum);
        for (int i = 0; i < 16; ++i) awb[tid * 16 + i] *= inv;
    }
    __syncthreads();

    // phase 1: bilinear sampling -> cf[p][d] = bf16(samp[d] * aw[p]); stage ba/wal
    ba[tid]  = bctx[tid] + obat[b * 768 + 256 + tid];
    wal[tid] = walpha[tid];
    {
        const int pg  = tid >> 2;
        const int sub = tid & 3;
        const int d0  = sub * 16;
        const int h   = pg >> 4;
        const int l   = (pg & 15) >> 2;
        const int Tlen = shapes[l];
        const int st   = starts[l];
        const float T  = (float)Tlen;
        const float refv = refp[b * 4 + l];
        const float offv = obat[b * 768 + pg];
        const float awv  = awb[pg];
        const float x   = (refv + offv * rcpf(T)) * T - 0.5f;  // exact: T is 2^k
        const float x0f = floorf(x);
        const float w1  = x - x0f;
        const int   x0  = (int)x0f;
        const float w0s = (x0 >= 0 && x0 < Tlen) ? (1.0f - w1) : 0.0f;
        const float w1s = (x0 + 1 >= 0 && x0 + 1 < Tlen) ? w1 : 0.0f;
        const int i0 = (min(max(x0, 0), Tlen - 1) + st) * 512 + h * 64;
        const int i1 = (min(max(x0 + 1, 0), Tlen - 1) + st) * 512 + h * 64;
        u16x8 o0, o1;
#pragma unroll
        for (int q = 0; q < 4; ++q) {
            const float4 a  = *(const float4*)&v[i0 + d0 + q * 4];
            const float4 bq = *(const float4*)&v[i1 + d0 + q * 4];
            unsigned short e0 = f2bf((a.x * w0s + bq.x * w1s) * awv);
            unsigned short e1 = f2bf((a.y * w0s + bq.y * w1s) * awv);
            unsigned short e2 = f2bf((a.z * w0s + bq.z * w1s) * awv);
            unsigned short e3 = f2bf((a.w * w0s + bq.w * w1s) * awv);
            if (q == 0) { o0[0] = e0; o0[1] = e1; o0[2] = e2; o0[3] = e3; }
            if (q == 1) { o0[4] = e0; o0[5] = e1; o0[6] = e2; o0[7] = e3; }
            if (q == 2) { o1[0] = e0; o1[1] = e1; o1[2] = e2; o1[3] = e3; }
            if (q == 3) { o1[4] = e0; o1[5] = e1; o1[6] = e2; o1[7] = e3; }
        }
        const int c0 = (sub * 2)     ^ (pg & 7);
        const int c1 = (sub * 2 + 1) ^ (pg & 7);
        *(u16x8*)&cf[pg * 64 + c0 * 8] = o0;
        *(u16x8*)&cf[pg * 64 + c1 * 8] = o1;
    }
    __syncthreads();

    // phase 2: dots[p] = sum_j tanh((cf@Wctx)[p][j] + ba[j]) * wal[j]  via MFMA
    {
        const int w    = tid >> 6, lane = tid & 63;
        const int wm   = w >> 2, wn = w & 3;
        const int lr   = lane & 15, lg = lane >> 4;

        s16x8 afrag[4][2];
#pragma unroll
        for (int mt = 0; mt < 4; ++mt) {
            const int row = wm * 64 + mt * 16 + lr;
#pragma unroll
            for (int ks = 0; ks < 2; ++ks) {
                const int ch = (ks * 4 + lg) ^ (row & 7);
                afrag[mt][ks] = *(const s16x8*)&cf[row * 64 + ch * 8];
            }
        }
        f32x4 part[4];
#pragma unroll
        for (int mt = 0; mt < 4; ++mt) part[mt] = (f32x4){0.f, 0.f, 0.f, 0.f};

#pragma clang loop unroll(disable)
        for (int nt = 0; nt < 8; ++nt) {
            const int ct  = wn * 8 + nt;
            const int col = ct * 16 + lr;
            const s16x8 b0 = *(const s16x8*)&Wb[col * 64 + lg * 8];
            const s16x8 b1 = *(const s16x8*)&Wb[col * 64 + 32 + lg * 8];
            const float bav = ba[col], wav = wal[col];
#pragma unroll
            for (int mt = 0; mt < 4; ++mt) {
                f32x4 acc = {0.f, 0.f, 0.f, 0.f};
                acc = __builtin_amdgcn_mfma_f32_16x16x32_bf16(afrag[mt][0], b0, acc, 0, 0, 0);
                acc = __builtin_amdgcn_mfma_f32_16x16x32_bf16(afrag[mt][1], b1, acc, 0, 0, 0);
#pragma unroll
                for (int r = 0; r < 4; ++r)
                    part[mt][r] += tanhf_fast(acc[r] + bav) * wav;
            }
        }
#pragma unroll
        for (int mt = 0; mt < 4; ++mt) {
#pragma unroll
            for (int r = 0; r < 4; ++r) {
                float s = part[mt][r];
                s += __shfl_xor(s, 1); s += __shfl_xor(s, 2);
                s += __shfl_xor(s, 4); s += __shfl_xor(s, 8);
                if (lr == 0) dots4[wn][wm * 64 + mt * 16 + lg * 4 + r] = s;
            }
        }
    }
    __syncthreads();
    if (tid < 128)
        dsum[tid] = dots4[0][tid] + dots4[1][tid] + dots4[2][tid] + dots4[3][tid];
    __syncthreads();

    // phase 3: softmax over the 16 points of each head
    if (tid < 8) {
        float mx = -1e30f;
        for (int i = 0; i < 16; ++i) mx = fmaxf(mx, dsum[tid * 16 + i]);
        float sum = 0.f;
        for (int i = 0; i < 16; ++i) { float e = exp2f_fast((dsum[tid * 16 + i] - mx) * LOG2E); dsum[tid * 16 + i] = e; sum += e; }
        float inv = rcpf(sum);
        for (int i = 0; i < 16; ++i) dsum[tid * 16 + i] *= inv;
    }
    __syncthreads();

    // phase 4: att_res (bf16 into Acat)
    {
        const int h = tid >> 6, d = tid & 63;
        const int ch = d >> 3, e = d & 7;
        float s = 0.f;
#pragma unroll
        for (int p = 0; p < 16; ++p) {
            const int row = h * 16 + p;
            s += dsum[h * 16 + p] * bf2f(cf[row * 64 + ((ch ^ (row & 7)) * 8) + e]);
        }
        attdst[(size_t)b * 2048 + tid] = f2bf(s);
    }
}

// LSTM elementwise; optionally emits bf16 h into hbf (row stride 1024)
__global__ __launch_bounds__(256) void lstm_act(
    const float* __restrict__ g, const float* __restrict__ c_in,
    float* __restrict__ h_out, float* __restrict__ h_out2,
    unsigned short* __restrict__ hbf, float* __restrict__ c_out)
{
    const int idx = blockIdx.x * 256 + threadIdx.x;  // 0..524287
    const int m = idx >> 9, j = idx & 511;
    const float* gr = g + (size_t)m * 2048;
    const float gi = gr[j], gf = gr[512 + j], gg = gr[1024 + j], go = gr[1536 + j];
    const float c  = c_in[idx];
    const float c2 = sigf(gf) * c + sigf(gi) * tanhf_fast(gg);
    const float h2 = sigf(go) * tanhf_fast(c2);
    h_out[idx] = h2;
    if (h_out2) h_out2[idx] = h2;
    if (hbf) hbf[(size_t)m * 1024 + j] = f2bf(h2);
    c_out[idx] = c2;
}

extern "C" void kernel_launch(void* const* d_in, const int* in_sizes, int n_in,
                              void* d_out, int out_size, void* d_ws, size_t ws_size,
                              hipStream_t stream) {
    const float* xt     = (const float*)d_in[0];
    const float* h0     = (const float*)d_in[1];   // (2,1024,512)
    const float* c0     = (const float*)d_in[2];
    const float* query  = (const float*)d_in[3];   // (1,1024,512)
    const float* refp   = (const float*)d_in[4];   // (1,1024,4,1)
    const float* inflat = (const float*)d_in[5];   // (1,1920,512)
    const int*   shapes = (const int*)d_in[6];
    const int*   starts = (const int*)d_in[7];
    const float* Wv     = (const float*)d_in[9];   // (512,512) (K,N)
    const float* bv     = (const float*)d_in[10];
    const float* Woff   = (const float*)d_in[11];  // (1024,128) (K,N)
    const float* boff   = (const float*)d_in[12];
    const float* Wattw  = (const float*)d_in[13];  // (1024,128)
    const float* battw  = (const float*)d_in[14];
    const float* Wctx   = (const float*)d_in[15];  // (64,512)
    const float* bctx   = (const float*)d_in[16];
    const float* Wh2a   = (const float*)d_in[17];  // (512,512) (K,N)
    const float* bh2a   = (const float*)d_in[18];
    const float* walpha = (const float*)d_in[19];
    const float* Wih0   = (const float*)d_in[21];  // (2048,1536) (N,K)
    const float* Whh0   = (const float*)d_in[22];  // (2048,512)
    const float* Wih1   = (const float*)d_in[23];  // (2048,512)
    const float* Whh1   = (const float*)d_in[24];  // (2048,512)

    float* out = (float*)d_out;
    float* ws  = (float*)d_ws;

    // ws layout (f32 units), lifetime-overlapped; total 8585216 f32 = 34.4 MB
    float*          v     = ws;                                   // 983040
    float*          obat  = ws + 983040;                          // 1024x768 [off|aw|atth]
    unsigned short* Acat  = (unsigned short*)(ws + 1769472);      // 1024x2048 bf16
    unsigned short* Bcat0 = (unsigned short*)(ws + 2818048);      // 2048x2048 bf16
    float*          g     = ws + 4915200;                         // 2097152
    //   early-phase tenants of the g region (dead before gemm0 writes g):
    unsigned short* Ainf  = (unsigned short*)(ws + 4915200);      // 1920x512 bf16
    unsigned short* Wvt   = (unsigned short*)(ws + 5406720);      // 512x512 bf16
    unsigned short* Wcat  = (unsigned short*)(ws + 5537792);      // 768x1024 bf16 [Woff^T|Wattw^T|Wh2a^T pad0]
    unsigned short* Ahq   = (unsigned short*)(ws + 5931008);      // 1024x1024 bf16
    unsigned short* Wb    = (unsigned short*)(ws + 6455296);      // 512x64 bf16 (Wctx^T)
    float*          bcat  = ws + 6471680;                         // 768
    unsigned short* Ag1   = (unsigned short*)(ws + 7012352);      // 1024x1024 bf16
    unsigned short* Bcat1 = (unsigned short*)(ws + 7536640);      // 2048x1024 bf16

    const float* h00    = h0;
    const float* h_last = h0 + 524288;     // h0[1]
    float* h1  = out + 524288;             // h_new[0]
    float* c1  = out + 1572864;            // c_new[0]
    float* h2a = out;                      // first output
    float* h2b = out + 1048576;            // h_new[1]
    float* c2  = out + 2097152;            // c_new[1]

    // --- prep: converts (1 launch), transposes + zero-pad (1 launch), biases ---
    { CvtJobs cj;
      cj.j[0]  = { xt,     Acat,          512,  2048, 512,  524288 };
      cj.j[1]  = { query,  Acat + 1024,   512,  2048, 512,  524288 };
      cj.j[2]  = { h00,    Acat + 1536,   512,  2048, 512,  524288 };
      cj.j[3]  = { h_last, Ahq,           512,  1024, 512,  524288 };
      cj.j[4]  = { query,  Ahq + 512,     512,  1024, 512,  524288 };
      cj.j[5]  = { h_last, Ag1 + 512,     512,  1024, 512,  524288 };
      cj.j[6]  = { Wih0,   Bcat0,         1536, 2048, 1536, 3145728 };
      cj.j[7]  = { Whh0,   Bcat0 + 1536,  512,  2048, 512,  1048576 };
      cj.j[8]  = { Wih1,   Bcat1,         512,  1024, 512,  1048576 };
      cj.j[9]  = { Whh1,   Bcat1 + 512,   512,  1024, 512,  1048576 };
      cj.j[10] = { inflat, Ainf,          512,  512,  512,  983040 };
      cvt_bf16<<<dim3(3072, 11), 256, 0, stream>>>(cj); }
    { TJobs tj;
      tj.j[0] = { Wv,      Wvt,                    512, 512,  512,  262144 };
      tj.j[1] = { Woff,    Wcat,                   128, 1024, 1024, 131072 };
      tj.j[2] = { Wattw,   Wcat + 128 * 1024,      128, 1024, 1024, 131072 };
      tj.j[3] = { Wh2a,    Wcat + 256 * 1024,      512, 1024, 512,  262144 };
      tj.j[4] = { Wctx,    Wb,                     512, 64,   64,   32768 };
      tj.j[5] = { nullptr, Wcat + 256 * 1024 + 512, 0,  1024, 512,  262144 }; // zero K-pad
      tcvt_bf16<<<dim3(1024, 6), 256, 0, stream>>>(tj); }
    bias_cat3<<<1, 768, 0, stream>>>(boff, battw, bh2a, bcat);

    // --- GEMMs (bf16 MFMA) ---
    // value: v = inflat @ Wv + bv          (1920x512, K=512)  [LDS-staged]
    sgemm<<<dim3(4, 30), 256, 0, stream>>>(Ainf, 512, Wvt, 512, bv, v, 512, 512);
    // obat = [h_last|query] @ [Woff|Wattw|Wh2a pad] + [boff|battw|bh2a]  (1024x768, K=1024)
    mgemm<<<dim3(12, 16), 256, 0, stream>>>(Ahq, 1024, Wcat, 1024, bcat, obat, 768, 1024);

    // --- fused deformable sampling + context attention (writes Acat[:,512:1024]) ---
    fused_att<<<1024, 512, 0, stream>>>(v, obat, refp, shapes, starts,
                                        Wb, bctx, walpha, Acat + 512);

    // g0 = [xt|att_res|query|h0[0]] @ [Wih0|Whh0]^T    (1024x2048, K=2048)  [LDS-staged]
    sgemm<<<dim3(16, 16), 256, 0, stream>>>(Acat, 2048, Bcat0, 2048, nullptr, g, 2048, 2048);
    lstm_act<<<2048, 256, 0, stream>>>(g, c0, h1, nullptr, Ag1, c1);
    // g1 = [h1|h0[1]] @ [Wih1|Whh1]^T                  (1024x2048, K=1024)  [LDS-staged]
    sgemm<<<dim3(16, 16), 256, 0, stream>>>(Ag1, 1024, Bcat1, 1024, nullptr, g, 2048, 1024);
    lstm_act<<<2048, 256, 0, stream>>>(g, c0 + 524288, h2a, h2b, nullptr, c2);
}